// Round 4
// baseline (7779.240 us; speedup 1.0000x reference)
//
#include <hip/hip_runtime.h>
#include <hip/hip_cooperative_groups.h>
#include <math.h>

namespace cg = cooperative_groups;

// DNC forward, cooperative v4: 96 specialized blocks, weights LDS-RESIDENT
// (loaded once, survive grid.sync). Roles: 0-31 LSTM0+outproj, 32-63
// LSTM1+interface, 64-95 memory module (per-batch M/L in LDS).

#define TT   64
#define BB   32
#define INW  64
#define OUTW 64
#define NN   128
#define WD   64
#define RR   4
#define HH   256
#define IFSZ 471
#define CLIPV 20.0f
#define EPSV  1e-6f

// interface vector offsets
#define OFF_RK   0
#define OFF_RSTR 256
#define OFF_WK   260
#define OFF_WSTR 324
#define OFF_ER   325
#define OFF_WV   389
#define OFF_FG   453
#define OFF_AG   457
#define OFF_WG   458
#define OFF_MD   459

// scal slots
#define S_WSTR 0
#define S_AG   1
#define S_WG   2
#define S_KNW  3
#define S_WSUM 4
#define S_RSTR 8
#define S_FG   12
#define S_KNR  16
#define S_BM   20
#define S_FM   24
#define S_CM   28

// ---- LDS layouts (floats) ----
// role A (LSTM0): Xs[320][36], Gl[32][32], c0sl[256], Go[64], Ws[576][36], Wout_s[512][2]
#define A_XS   0
#define A_GL   11520
#define A_C0   12544
#define A_GO   12800
#define A_WS   12864
#define A_WO   33600
// role B (LSTM1+IF): Xs[320][36], Gl, c1sl, W1[512][36], Wif[256][20]
#define B_XS   0
#define B_GL   11520
#define B_C1   12544
#define B_W1   12864
#define B_WIF  31296
// role C (memory): Ms[128][65], Ls[128][129], state+scratch
#define C_MS   0
#define C_LS   8320
#define C_WW   24832
#define C_PRC  24960
#define C_USG  25088
#define C_RWS  25216
#define C_IFC  25728
#define C_FWD  26208
#define C_BWD  26720
#define C_U2   27232
#define C_WCS  27360
#define C_RCS  27488
#define C_MNO  28000
#define C_RDS  28128
#define C_ERS  28384
#define C_WVS  28448
#define C_SC   28512
#define C_SCAL 28576

#define SMEM_FLOATS 36448
#define SMEM_BYTES  (SMEM_FLOATS*4)

// ---- ws layout (floats), all state vectors transposed [k][b] ----
#define W_CTL  0       // [256][32]
#define W_RDS  8192    // [256][32]
#define W_H0   16384   // [2][256*32]
#define W_H1   32768   // [2][256*32]
#define W_IFC  49152   // [471][32]
#define W_TOTAL 64224

__device__ __forceinline__ float sigf(float x){ return 1.0f/(1.0f+expf(-x)); }
__device__ __forceinline__ float sofp(float x){ return fmaxf(x,0.0f)+log1pf(expf(-fabsf(x))); }

__device__ __forceinline__ float wredSum(float v){
  #pragma unroll
  for (int m=32;m>0;m>>=1) v += __shfl_xor(v,m,64);
  return v;
}
__device__ __forceinline__ float wredMax(float v){
  #pragma unroll
  for (int m=32;m>0;m>>=1) v = fmaxf(v,__shfl_xor(v,m,64));
  return v;
}

// 6-stage butterfly reduce-scatter over 64 lanes; A[64] in regs; returns the
// single fully-reduced element this lane owns; *jb = its logical index
// (bit-reverse of lane).
__device__ __forceinline__ float bfly64(float (&A)[64], int l, int* jb){
  #pragma unroll
  for (int st=0; st<6; ++st){
    const int m = 1<<st, half = 32>>st;
    const bool hi = (l & m) != 0;
    #pragma unroll
    for (int j=0;j<half;j++){
      float a = A[j], b = A[j+half];
      float keep = hi? b : a;
      float send = hi? a : b;
      A[j] = keep + __shfl_xor(send, m, 64);
    }
  }
  *jb = ((l&1)?32:0)|((l&2)?16:0)|((l&4)?8:0)|((l&8)?4:0)|((l&16)?2:0)|((l&32)?1:0);
  return A[0];
}

extern "C" __global__ __launch_bounds__(1024, 1)
void dnc_coop4(const float* __restrict__ inputs,
               const float* __restrict__ Wx0, const float* __restrict__ Wh0, const float* __restrict__ b0g,
               const float* __restrict__ Wx1, const float* __restrict__ Wh1, const float* __restrict__ b1g,
               const float* __restrict__ Wifg, const float* __restrict__ bifg,
               const float* __restrict__ Woutg, const float* __restrict__ boutg,
               float* __restrict__ outg, float* __restrict__ ws)
{
  cg::grid_group grid = cg::this_grid();
  const int role = blockIdx.x >> 5;   // 0,1,2
  const int g    = blockIdx.x & 31;
  const int tid  = threadIdx.x;
  const int lane = tid & 63;
  const int wid  = tid >> 6;

  extern __shared__ float sm[];

  float* gctl  = ws + W_CTL;
  float* greads= ws + W_RDS;
  float* gifc  = ws + W_IFC;

  // ---- zero ws ----
  for (int i = blockIdx.x*1024 + tid; i < W_TOTAL; i += 96*1024) ws[i] = 0.0f;

  // ---- one-time weight staging + state init ----
  if (role == 0){
    // Ws: rows 0-319 = Wx0, 320-575 = Wh0; cols interleaved gate layout
    for (int i = tid; i < 576*32; i += 1024){
      int k = i >> 5, cl = i & 31;
      int cglob = 8*g + (cl&7) + (cl>>3)*256;
      sm[A_WS + k*36 + cl] = (k < 320) ? Wx0[k*1024 + cglob]
                                       : Wh0[(k-320)*1024 + cglob];
    }
    for (int i = tid; i < 512*2; i += 1024){
      int k = i >> 1, c = i & 1;
      sm[A_WO + i] = Woutg[k*64 + 2*g + c];
    }
    if (tid < 256) sm[A_C0 + tid] = 0.0f;
  } else if (role == 1){
    for (int i = tid; i < 512*32; i += 1024){
      int k = i >> 5, cl = i & 31;
      int cglob = 8*g + (cl&7) + (cl>>3)*256;
      sm[B_W1 + k*36 + cl] = (k < 256) ? Wx1[k*1024 + cglob]
                                       : Wh1[(k-256)*1024 + cglob];
    }
    for (int i = tid; i < 256*16; i += 1024){
      int k = i >> 4, c = i & 15;
      int col = g*15 + c;
      sm[B_WIF + k*20 + c] = (c < 15 && col < IFSZ) ? Wifg[k*IFSZ + col] : 0.0f;
    }
    if (tid < 256) sm[B_C1 + tid] = 0.0f;
  } else {
    for (int i = tid; i < NN*65;  i += 1024) sm[C_MS + i] = 0.0f;
    for (int i = tid; i < NN*129; i += 1024) sm[C_LS + i] = 0.0f;
    if (tid < 128){ sm[C_WW+tid]=0.f; sm[C_PRC+tid]=0.f; sm[C_USG+tid]=0.f; }
    if (tid < 512) sm[C_RWS+tid]=0.f;
  }
  __syncthreads();
  grid.sync();

  for (int t = 0; t <= TT; ++t){
    float* h0old = ws + W_H0 + (t&1)*8192;
    float* h0new = ws + W_H0 + ((t+1)&1)*8192;
    float* h1old = ws + W_H1 + (t&1)*8192;
    float* h1new = ws + W_H1 + ((t+1)&1)*8192;

    // ============ phase1: role A — outproj(t-1) + LSTM0 gates ============
    if (role == 0){
      float* Xs = sm + A_XS;
      if (t > 0){
        float accO[16];
        #pragma unroll
        for (int j=0;j<16;j++) accO[j]=0.f;
        // O1: x = ctl
        for (int i = tid; i < 256*32; i += 1024){
          int k = i>>5, bb = i&31; Xs[k*36+bb] = gctl[i];
        }
        __syncthreads();
        if (wid < 4){
          const int b0 = wid*8;
          #pragma unroll
          for (int i=0;i<4;i++){
            int k = lane*4 + i;
            float2 w2 = *reinterpret_cast<const float2*>(&sm[A_WO + k*2]);
            float4 x0 = *reinterpret_cast<const float4*>(&Xs[k*36+b0]);
            float4 x1 = *reinterpret_cast<const float4*>(&Xs[k*36+b0+4]);
            float xv[8] = {x0.x,x0.y,x0.z,x0.w,x1.x,x1.y,x1.z,x1.w};
            #pragma unroll
            for (int bi=0;bi<8;bi++){
              accO[bi*2]   += xv[bi]*w2.x;
              accO[bi*2+1] += xv[bi]*w2.y;
            }
          }
        }
        __syncthreads();
        // O2: x = reads
        for (int i = tid; i < 256*32; i += 1024){
          int k = i>>5, bb = i&31; Xs[k*36+bb] = greads[i];
        }
        __syncthreads();
        if (wid < 4){
          const int b0 = wid*8;
          #pragma unroll
          for (int i=0;i<4;i++){
            int k = lane*4 + i;
            float2 w2 = *reinterpret_cast<const float2*>(&sm[A_WO + (256+k)*2]);
            float4 x0 = *reinterpret_cast<const float4*>(&Xs[k*36+b0]);
            float4 x1 = *reinterpret_cast<const float4*>(&Xs[k*36+b0+4]);
            float xv[8] = {x0.x,x0.y,x0.z,x0.w,x1.x,x1.y,x1.z,x1.w};
            #pragma unroll
            for (int bi=0;bi<8;bi++){
              accO[bi*2]   += xv[bi]*w2.x;
              accO[bi*2+1] += xv[bi]*w2.y;
            }
          }
          // reduce: 4 scatter stages within 16-lane groups, 2 allreduce stages
          #pragma unroll
          for (int st=0; st<4; ++st){
            const int m = 1<<st, half = 8>>st;
            const bool hi = (lane & m) != 0;
            #pragma unroll
            for (int j=0;j<half;j++){
              float a = accO[j], b = accO[j+half];
              float keep = hi? b : a;
              float send = hi? a : b;
              accO[j] = keep + __shfl_xor(send, m, 64);
            }
          }
          accO[0] += __shfl_xor(accO[0], 16, 64);
          accO[0] += __shfl_xor(accO[0], 32, 64);
          int jb = ((lane&1)?8:0)|((lane&2)?4:0)|((lane&4)?2:0)|((lane&8)?1:0);
          if ((lane & 48) == 0){
            int bi = jb>>1, ci = jb&1;
            sm[A_GO + (wid*8+bi)*2 + ci] = accO[0];
          }
        }
        __syncthreads();
        if (tid < 64){
          int bb = tid>>1, c = tid&1;
          float v = sm[A_GO + tid] + boutg[2*g + c];
          outg[((t-1)*BB + bb)*OUTW + 2*g + c] = fminf(CLIPV, fmaxf(-CLIPV, v));
        }
        __syncthreads();
      }
      if (t < TT){
        float acc[64];
        #pragma unroll
        for (int j=0;j<64;j++) acc[j]=0.f;
        // chunk1: ctrl_in = [x_t(64) | reads(256)]
        for (int i = tid; i < 64*32; i += 1024){
          int bb = i>>6, k = i&63;
          Xs[k*36+bb] = inputs[(t*BB + bb)*INW + k];
        }
        for (int i = tid; i < 256*32; i += 1024){
          int k = i>>5, bb = i&31;
          Xs[(64+k)*36+bb] = greads[i];
        }
        __syncthreads();
        {
          const int b0 = (wid>>2)*8, c0 = (wid&3)*8;
          #pragma unroll
          for (int i=0;i<5;i++){
            int k = lane*5 + i;
            float4 w0 = *reinterpret_cast<const float4*>(&sm[A_WS + k*36+c0]);
            float4 w1 = *reinterpret_cast<const float4*>(&sm[A_WS + k*36+c0+4]);
            float4 x0 = *reinterpret_cast<const float4*>(&Xs[k*36+b0]);
            float4 x1 = *reinterpret_cast<const float4*>(&Xs[k*36+b0+4]);
            float xv[8] = {x0.x,x0.y,x0.z,x0.w,x1.x,x1.y,x1.z,x1.w};
            float wv[8] = {w0.x,w0.y,w0.z,w0.w,w1.x,w1.y,w1.z,w1.w};
            #pragma unroll
            for (int bi=0;bi<8;bi++)
              #pragma unroll
              for (int ci=0;ci<8;ci++)
                acc[bi*8+ci] += xv[bi]*wv[ci];
          }
        }
        __syncthreads();
        // chunk2: h0old
        for (int i = tid; i < 256*32; i += 1024){
          int k = i>>5, bb = i&31; Xs[k*36+bb] = h0old[i];
        }
        __syncthreads();
        {
          const int b0 = (wid>>2)*8, c0 = (wid&3)*8;
          #pragma unroll
          for (int i=0;i<4;i++){
            int k = lane*4 + i;
            float4 w0 = *reinterpret_cast<const float4*>(&sm[A_WS + (320+k)*36+c0]);
            float4 w1 = *reinterpret_cast<const float4*>(&sm[A_WS + (320+k)*36+c0+4]);
            float4 x0 = *reinterpret_cast<const float4*>(&Xs[k*36+b0]);
            float4 x1 = *reinterpret_cast<const float4*>(&Xs[k*36+b0+4]);
            float xv[8] = {x0.x,x0.y,x0.z,x0.w,x1.x,x1.y,x1.z,x1.w};
            float wv[8] = {w0.x,w0.y,w0.z,w0.w,w1.x,w1.y,w1.z,w1.w};
            #pragma unroll
            for (int bi=0;bi<8;bi++)
              #pragma unroll
              for (int ci=0;ci<8;ci++)
                acc[bi*8+ci] += xv[bi]*wv[ci];
          }
          int jb; float v = bfly64(acc, lane, &jb);
          const int b0w = (wid>>2)*8, c0w = (wid&3)*8;
          sm[A_GL + (b0w + (jb>>3))*32 + c0w + (jb&7)] = v;
        }
        __syncthreads();
        if (tid < 256){
          int bb = tid>>3, j = tid&7;
          float gi = sm[A_GL + bb*32 + j]      + b0g[8*g + j];
          float gf = sm[A_GL + bb*32 + 8 + j]  + b0g[256 + 8*g + j];
          float gg = sm[A_GL + bb*32 + 16 + j] + b0g[512 + 8*g + j];
          float go = sm[A_GL + bb*32 + 24 + j] + b0g[768 + 8*g + j];
          float c = sigf(gf)*sm[A_C0+tid] + sigf(gi)*tanhf(gg);
          sm[A_C0+tid] = c;
          h0new[(8*g + j)*32 + bb] = sigf(go)*tanhf(c);
        }
      }
    }
    if (t == TT) break;
    grid.sync();

    // ============ phase2: role B — LSTM1 gates ============
    if (role == 1){
      float* Xs = sm + B_XS;
      float acc[64];
      #pragma unroll
      for (int j=0;j<64;j++) acc[j]=0.f;
      // chunk1: h0new
      for (int i = tid; i < 256*32; i += 1024){
        int k = i>>5, bb = i&31; Xs[k*36+bb] = h0new[i];
      }
      __syncthreads();
      {
        const int b0 = (wid>>2)*8, c0 = (wid&3)*8;
        #pragma unroll
        for (int i=0;i<4;i++){
          int k = lane*4 + i;
          float4 w0 = *reinterpret_cast<const float4*>(&sm[B_W1 + k*36+c0]);
          float4 w1 = *reinterpret_cast<const float4*>(&sm[B_W1 + k*36+c0+4]);
          float4 x0 = *reinterpret_cast<const float4*>(&Xs[k*36+b0]);
          float4 x1 = *reinterpret_cast<const float4*>(&Xs[k*36+b0+4]);
          float xv[8] = {x0.x,x0.y,x0.z,x0.w,x1.x,x1.y,x1.z,x1.w};
          float wv[8] = {w0.x,w0.y,w0.z,w0.w,w1.x,w1.y,w1.z,w1.w};
          #pragma unroll
          for (int bi=0;bi<8;bi++)
            #pragma unroll
            for (int ci=0;ci<8;ci++)
              acc[bi*8+ci] += xv[bi]*wv[ci];
        }
      }
      __syncthreads();
      // chunk2: h1old
      for (int i = tid; i < 256*32; i += 1024){
        int k = i>>5, bb = i&31; Xs[k*36+bb] = h1old[i];
      }
      __syncthreads();
      {
        const int b0 = (wid>>2)*8, c0 = (wid&3)*8;
        #pragma unroll
        for (int i=0;i<4;i++){
          int k = lane*4 + i;
          float4 w0 = *reinterpret_cast<const float4*>(&sm[B_W1 + (256+k)*36+c0]);
          float4 w1 = *reinterpret_cast<const float4*>(&sm[B_W1 + (256+k)*36+c0+4]);
          float4 x0 = *reinterpret_cast<const float4*>(&Xs[k*36+b0]);
          float4 x1 = *reinterpret_cast<const float4*>(&Xs[k*36+b0+4]);
          float xv[8] = {x0.x,x0.y,x0.z,x0.w,x1.x,x1.y,x1.z,x1.w};
          float wv[8] = {w0.x,w0.y,w0.z,w0.w,w1.x,w1.y,w1.z,w1.w};
          #pragma unroll
          for (int bi=0;bi<8;bi++)
            #pragma unroll
            for (int ci=0;ci<8;ci++)
              acc[bi*8+ci] += xv[bi]*wv[ci];
        }
        int jb; float v = bfly64(acc, lane, &jb);
        const int b0w = (wid>>2)*8, c0w = (wid&3)*8;
        sm[B_GL + (b0w + (jb>>3))*32 + c0w + (jb&7)] = v;
      }
      __syncthreads();
      if (tid < 256){
        int bb = tid>>3, j = tid&7;
        float gi = sm[B_GL + bb*32 + j]      + b1g[8*g + j];
        float gf = sm[B_GL + bb*32 + 8 + j]  + b1g[256 + 8*g + j];
        float gg = sm[B_GL + bb*32 + 16 + j] + b1g[512 + 8*g + j];
        float go = sm[B_GL + bb*32 + 24 + j] + b1g[768 + 8*g + j];
        float c = sigf(gf)*sm[B_C1+tid] + sigf(gi)*tanhf(gg);
        sm[B_C1+tid] = c;
        float h = sigf(go)*tanhf(c);
        h1new[(8*g + j)*32 + bb] = h;
        gctl[(8*g + j)*32 + bb]  = fminf(CLIPV, fmaxf(-CLIPV, h));
      }
    }
    grid.sync();

    // ============ phase3: role B — interface vector ============
    if (role == 1){
      float* Xs = sm + B_XS;
      for (int i = tid; i < 256*32; i += 1024){
        int k = i>>5, bb = i&31; Xs[k*36+bb] = gctl[i];
      }
      __syncthreads();
      if (wid < 8){
        float acc[64];
        #pragma unroll
        for (int j=0;j<64;j++) acc[j]=0.f;
        const int b0 = (wid>>1)*8, c0 = (wid&1)*8;
        #pragma unroll
        for (int i=0;i<4;i++){
          int k = lane*4 + i;
          float4 w0 = *reinterpret_cast<const float4*>(&sm[B_WIF + k*20+c0]);
          float4 w1 = *reinterpret_cast<const float4*>(&sm[B_WIF + k*20+c0+4]);
          float4 x0 = *reinterpret_cast<const float4*>(&Xs[k*36+b0]);
          float4 x1 = *reinterpret_cast<const float4*>(&Xs[k*36+b0+4]);
          float xv[8] = {x0.x,x0.y,x0.z,x0.w,x1.x,x1.y,x1.z,x1.w};
          float wv[8] = {w0.x,w0.y,w0.z,w0.w,w1.x,w1.y,w1.z,w1.w};
          #pragma unroll
          for (int bi=0;bi<8;bi++)
            #pragma unroll
            for (int ci=0;ci<8;ci++)
              acc[bi*8+ci] += xv[bi]*wv[ci];
        }
        int jb; float v = bfly64(acc, lane, &jb);
        int bi = jb>>3, ci = jb&7;
        int cl = c0 + ci;
        const int ncols = (g < 31) ? 15 : 6;
        if (cl < ncols){
          int col = g*15 + cl;
          gifc[col*32 + (b0+bi)] = v + bifg[col];
        }
      }
    }
    grid.sync();

    // ============ phase4: role C — memory module (batch g) ============
    if (role == 2){
      float* Ms  = sm + C_MS;
      float* Ls  = sm + C_LS;
      float* wws = sm + C_WW;
      float* prc = sm + C_PRC;
      float* usg = sm + C_USG;
      float* rws = sm + C_RWS;
      float* ifcl= sm + C_IFC;
      float* fwds= sm + C_FWD;
      float* bwds= sm + C_BWD;
      float* u2  = sm + C_U2;
      float* wcs = sm + C_WCS;
      float* rcs = sm + C_RCS;
      float* mno = sm + C_MNO;
      float* rds = sm + C_RDS;
      float* ers = sm + C_ERS;
      float* wvs = sm + C_WVS;
      float* sc  = sm + C_SC;
      float* scal= sm + C_SCAL;

      if (tid < IFSZ) ifcl[tid] = gifc[tid*32 + g];
      __syncthreads();
      if (tid < RR){
        scal[S_RSTR+tid]=1.0f+sofp(ifcl[OFF_RSTR+tid]);
        scal[S_FG+tid]  =sigf(ifcl[OFF_FG+tid]);
        float m0=ifcl[OFF_MD+tid*3], m1=ifcl[OFF_MD+tid*3+1], m2=ifcl[OFF_MD+tid*3+2];
        float mx=fmaxf(m0,fmaxf(m1,m2));
        float e0=expf(m0-mx), e1=expf(m1-mx), e2=expf(m2-mx);
        float s=e0+e1+e2;
        scal[S_BM+tid]=e0/s; scal[S_FM+tid]=e1/s; scal[S_CM+tid]=e2/s;
      }
      if (tid == 4) scal[S_WSTR]=1.0f+sofp(ifcl[OFF_WSTR]);
      if (tid == 5) scal[S_AG]=sigf(ifcl[OFF_AG]);
      if (tid == 6) scal[S_WG]=sigf(ifcl[OFF_WG]);
      if (tid >= 64 && tid < 128){
        int d=tid-64;
        ers[d]=sigf(ifcl[OFF_ER+d]);
        wvs[d]=ifcl[OFF_WV+d];
      }
      if (tid >= 128 && tid < 256){
        int n=tid-128; float s=0.f;
        #pragma unroll 8
        for (int d=0;d<WD;d++){ float v=Ms[n*65+d]; s+=v*v; }
        mno[n]=sqrtf(s);
      }
      if (wid == 8){
        float v=ifcl[OFF_WK+lane]; float s=wredSum(v*v);
        if (lane==0) scal[S_KNW]=sqrtf(s);
      }
      if (wid >= 10 && wid < 14){
        int r=wid-10; float v=ifcl[OFF_RK+r*WD+lane]; float s=wredSum(v*v);
        if (lane==0) scal[S_KNR+r]=sqrtf(s);
      }
      __syncthreads();
      if (tid < NN){
        float dot=0.f;
        #pragma unroll 8
        for (int d=0;d<WD;d++) dot += ifcl[OFF_WK+d]*Ms[tid*65+d];
        float sim = dot/(scal[S_KNW]*mno[tid]+EPSV);
        wcs[tid]=sim*scal[S_WSTR];
      }
      __syncthreads();
      if (tid < NN){ float mx=wredMax(wcs[tid]); if(lane==0) sc[wid]=mx; }
      __syncthreads();
      if (tid < NN){
        float mx=fmaxf(sc[0],sc[1]);
        float e=expf(wcs[tid]-mx);
        wcs[tid]=e;
        float s=wredSum(e); if(lane==0) sc[2+wid]=s;
      }
      __syncthreads();
      if (tid < NN) wcs[tid]=wcs[tid]/(sc[2]+sc[3]);
      __syncthreads();
      if (tid < NN){
        float cw = wws[tid];
        float u  = usg[tid] + (1.0f-usg[tid])*cw;
        float psi=1.0f;
        #pragma unroll
        for (int r=0;r<RR;r++) psi *= 1.0f - scal[S_FG+r]*rws[r*NN+tid];
        float us = u*psi;
        usg[tid]=us;
        u2[tid] = EPSV + (1.0f-EPSV)*us;
      }
      __syncthreads();
      if (tid < NN){
        float ui=u2[tid]; float p=1.0f;
        for (int j=0;j<NN;j++){
          float uj=u2[j];
          bool take = (uj<ui) || (uj==ui && j<tid);
          p *= take ? uj : 1.0f;
        }
        float a = (1.0f-ui)*p;
        float wwn = scal[S_WG]*( scal[S_AG]*a + (1.0f-scal[S_AG])*wcs[tid] );
        wws[tid]=wwn;
        float s=wredSum(wwn); if(lane==0) sc[wid]=s;
      }
      __syncthreads();
      if (tid==0) scal[S_WSUM]=sc[0]+sc[1];
      __syncthreads();
      #pragma unroll
      for (int i=0;i<8;i++){
        int el=tid+i*1024, n=el>>6, d=el&63;
        float w=wws[n];
        Ms[n*65+d] = Ms[n*65+d]*(1.0f - w*ers[d]) + w*wvs[d];
      }
      #pragma unroll
      for (int i=0;i<16;i++){
        int el=tid+i*1024, li=el>>7, lj=el&127;
        float v = (li==lj) ? 0.0f
                : (1.0f - wws[li] - wws[lj])*Ls[li*129+lj] + wws[li]*prc[lj];
        Ls[li*129+lj]=v;
      }
      __syncthreads();
      if (tid < NN) prc[tid] = (1.0f - scal[S_WSUM])*prc[tid] + wws[tid];
      if (tid >= 128 && tid < 256){
        int n=tid-128; float s=0.f;
        #pragma unroll 8
        for (int d=0;d<WD;d++){ float v=Ms[n*65+d]; s+=v*v; }
        mno[n]=sqrtf(s);
      }
      __syncthreads();
      if (tid < RR*NN){
        int r=tid>>7, n=tid&127;
        float dot=0.f;
        #pragma unroll 8
        for (int d=0;d<WD;d++) dot += ifcl[OFF_RK+r*WD+d]*Ms[n*65+d];
        float sim = dot/(scal[S_KNR+r]*mno[n]+EPSV);
        rcs[tid]=sim*scal[S_RSTR+r];
      }
      __syncthreads();
      if (tid < RR*NN){ float mx=wredMax(rcs[tid]); if(lane==0) sc[wid]=mx; }
      __syncthreads();
      if (tid < RR*NN){
        int r=tid>>7;
        float mx=fmaxf(sc[r*2],sc[r*2+1]);
        float e=expf(rcs[tid]-mx);
        rcs[tid]=e;
        float s=wredSum(e); if(lane==0) sc[8+wid]=s;
      }
      __syncthreads();
      if (tid < RR*NN){
        int r=tid>>7;
        rcs[tid]=rcs[tid]/(sc[8+r*2]+sc[9+r*2]);
      }
      __syncthreads();
      if (tid < RR*NN){
        int r=tid>>7, i=tid&127;
        float f=0.f, bw=0.f;
        const float* rwr = rws + r*NN;
        #pragma unroll 4
        for (int j=0;j<NN;j++){
          float rv=rwr[j];
          f  += Ls[i*129+j]*rv;
          bw += Ls[j*129+i]*rv;
        }
        fwds[tid]=f; bwds[tid]=bw;
      }
      __syncthreads();
      if (tid < RR*NN){
        int r=tid>>7;
        rws[tid] = scal[S_BM+r]*bwds[tid] + scal[S_CM+r]*rcs[tid] + scal[S_FM+r]*fwds[tid];
      }
      __syncthreads();
      if (tid < RR*WD){
        int r=tid>>6, d=tid&63;
        float s=0.f;
        #pragma unroll 8
        for (int n=0;n<NN;n++) s += rws[r*NN+n]*Ms[n*65+d];
        rds[tid]=s;
      }
      __syncthreads();
      if (tid < 256) greads[tid*32 + g] = rds[tid];
    }
    grid.sync();
  }
}

extern "C" void kernel_launch(void* const* d_in, const int* in_sizes, int n_in,
                              void* d_out, int out_size, void* d_ws, size_t ws_size,
                              hipStream_t stream)
{
  const float* inputs=(const float*)d_in[0];
  const float* Wx0   =(const float*)d_in[1];
  const float* Wh0   =(const float*)d_in[2];
  const float* b0    =(const float*)d_in[3];
  const float* Wx1   =(const float*)d_in[4];
  const float* Wh1   =(const float*)d_in[5];
  const float* b1    =(const float*)d_in[6];
  const float* Wif   =(const float*)d_in[7];
  const float* bif   =(const float*)d_in[8];
  const float* Wout  =(const float*)d_in[9];
  const float* bout  =(const float*)d_in[10];
  float* out = (float*)d_out;
  float* ws  = (float*)d_ws;

  hipFuncSetAttribute((const void*)dnc_coop4,
                      hipFuncAttributeMaxDynamicSharedMemorySize, SMEM_BYTES);

  void* args[] = { (void*)&inputs, (void*)&Wx0, (void*)&Wh0, (void*)&b0,
                   (void*)&Wx1, (void*)&Wh1, (void*)&b1, (void*)&Wif,
                   (void*)&bif, (void*)&Wout, (void*)&bout, (void*)&out,
                   (void*)&ws };
  hipLaunchCooperativeKernel((void*)dnc_coop4, dim3(96), dim3(1024),
                             args, SMEM_BYTES, stream);
}

// Round 5
// 6192.373 us; speedup vs baseline: 1.2563x; 1.2563x over previous
//
#include <hip/hip_runtime.h>
#include <math.h>

// DNC forward, cooperative v5: R4 structure (96 specialized blocks, weights
// LDS-resident) but grid.sync() replaced by a custom lightweight barrier:
// monotonic counter + agent-scope atomics (coherent at die-level LLC, no L2
// flush). All cross-block ws traffic via agent-scope relaxed atomic ld/st.

#define TT   64
#define BB   32
#define INW  64
#define OUTW 64
#define NN   128
#define WD   64
#define RR   4
#define HH   256
#define IFSZ 471
#define CLIPV 20.0f
#define EPSV  1e-6f
#define NBLK 96

// interface vector offsets
#define OFF_RK   0
#define OFF_RSTR 256
#define OFF_WK   260
#define OFF_WSTR 324
#define OFF_ER   325
#define OFF_WV   389
#define OFF_FG   453
#define OFF_AG   457
#define OFF_WG   458
#define OFF_MD   459

// scal slots
#define S_WSTR 0
#define S_AG   1
#define S_WG   2
#define S_KNW  3
#define S_WSUM 4
#define S_RSTR 8
#define S_FG   12
#define S_KNR  16
#define S_BM   20
#define S_FM   24
#define S_CM   28

// ---- LDS layouts (floats) ----
#define A_XS   0
#define A_GL   11520
#define A_C0   12544
#define A_GO   12800
#define A_WS   12864
#define A_WO   33600
#define B_XS   0
#define B_GL   11520
#define B_C1   12544
#define B_W1   12864
#define B_WIF  31296
#define C_MS   0
#define C_LS   8320
#define C_WW   24832
#define C_PRC  24960
#define C_USG  25088
#define C_RWS  25216
#define C_IFC  25728
#define C_FWD  26208
#define C_BWD  26720
#define C_U2   27232
#define C_WCS  27360
#define C_RCS  27488
#define C_MNO  28000
#define C_RDS  28128
#define C_ERS  28384
#define C_WVS  28448
#define C_SC   28512
#define C_SCAL 28576

#define SMEM_FLOATS 36448
#define SMEM_BYTES  (SMEM_FLOATS*4)

// ---- ws layout (floats), state vectors transposed [k][b] ----
#define W_CTL  0       // [256][32]
#define W_RDS  8192    // [256][32]
#define W_H0   16384   // [2][256*32]
#define W_H1   32768   // [2][256*32]
#define W_IFC  49152   // [471][32]
#define W_TOTAL 64224
#define W_BAR  64256   // barrier counter (16B-aligned slot)

__device__ __forceinline__ float sigf(float x){ return 1.0f/(1.0f+expf(-x)); }
__device__ __forceinline__ float sofp(float x){ return fmaxf(x,0.0f)+log1pf(expf(-fabsf(x))); }

// agent-scope (device) coherent accessors for cross-block ws data
__device__ __forceinline__ float gload(const float* p){
  return __hip_atomic_load(p, __ATOMIC_RELAXED, __HIP_MEMORY_SCOPE_AGENT);
}
__device__ __forceinline__ void gstore(float* p, float v){
  __hip_atomic_store(p, v, __ATOMIC_RELAXED, __HIP_MEMORY_SCOPE_AGENT);
}

// lightweight grid barrier: monotonic counter, agent-scope atomics.
// Every block must call with the same sequence of targets.
__device__ __forceinline__ void gbar(unsigned* w, unsigned target){
  asm volatile("s_waitcnt vmcnt(0)" ::: "memory");   // this wave's stores done
  __syncthreads();                                   // all waves drained (compiler adds vmcnt(0) before s_barrier)
  if (threadIdx.x == 0){
    __hip_atomic_fetch_add(w, 1u, __ATOMIC_RELAXED, __HIP_MEMORY_SCOPE_AGENT);
    while (__hip_atomic_load(w, __ATOMIC_RELAXED, __HIP_MEMORY_SCOPE_AGENT) < target)
      __builtin_amdgcn_s_sleep(2);
  }
  __syncthreads();
}

__device__ __forceinline__ float wredSum(float v){
  #pragma unroll
  for (int m=32;m>0;m>>=1) v += __shfl_xor(v,m,64);
  return v;
}
__device__ __forceinline__ float wredMax(float v){
  #pragma unroll
  for (int m=32;m>0;m>>=1) v = fmaxf(v,__shfl_xor(v,m,64));
  return v;
}

// 6-stage butterfly reduce-scatter over 64 lanes
__device__ __forceinline__ float bfly64(float (&A)[64], int l, int* jb){
  #pragma unroll
  for (int st=0; st<6; ++st){
    const int m = 1<<st, half = 32>>st;
    const bool hi = (l & m) != 0;
    #pragma unroll
    for (int j=0;j<half;j++){
      float a = A[j], b = A[j+half];
      float keep = hi? b : a;
      float send = hi? a : b;
      A[j] = keep + __shfl_xor(send, m, 64);
    }
  }
  *jb = ((l&1)?32:0)|((l&2)?16:0)|((l&4)?8:0)|((l&8)?4:0)|((l&16)?2:0)|((l&32)?1:0);
  return A[0];
}

extern "C" __global__ __launch_bounds__(1024, 1)
void dnc_coop5(const float* __restrict__ inputs,
               const float* __restrict__ Wx0, const float* __restrict__ Wh0, const float* __restrict__ b0g,
               const float* __restrict__ Wx1, const float* __restrict__ Wh1, const float* __restrict__ b1g,
               const float* __restrict__ Wifg, const float* __restrict__ bifg,
               const float* __restrict__ Woutg, const float* __restrict__ boutg,
               float* __restrict__ outg, float* __restrict__ ws)
{
  const int role = blockIdx.x >> 5;   // 0,1,2
  const int g    = blockIdx.x & 31;
  const int tid  = threadIdx.x;
  const int lane = tid & 63;
  const int wid  = tid >> 6;

  extern __shared__ float sm[];

  float* gctl  = ws + W_CTL;
  float* greads= ws + W_RDS;
  float* gifc  = ws + W_IFC;
  unsigned* barw = (unsigned*)(ws + W_BAR);
  unsigned bar_t = 0;

  // ---- one-time weight staging + state init (ws zeroed by host memset) ----
  if (role == 0){
    for (int i = tid; i < 576*32; i += 1024){
      int k = i >> 5, cl = i & 31;
      int cglob = 8*g + (cl&7) + (cl>>3)*256;
      sm[A_WS + k*36 + cl] = (k < 320) ? Wx0[k*1024 + cglob]
                                       : Wh0[(k-320)*1024 + cglob];
    }
    for (int i = tid; i < 512*2; i += 1024){
      int k = i >> 1, c = i & 1;
      sm[A_WO + i] = Woutg[k*64 + 2*g + c];
    }
    if (tid < 256) sm[A_C0 + tid] = 0.0f;
  } else if (role == 1){
    for (int i = tid; i < 512*32; i += 1024){
      int k = i >> 5, cl = i & 31;
      int cglob = 8*g + (cl&7) + (cl>>3)*256;
      sm[B_W1 + k*36 + cl] = (k < 256) ? Wx1[k*1024 + cglob]
                                       : Wh1[(k-256)*1024 + cglob];
    }
    for (int i = tid; i < 256*16; i += 1024){
      int k = i >> 4, c = i & 15;
      int col = g*15 + c;
      sm[B_WIF + k*20 + c] = (c < 15 && col < IFSZ) ? Wifg[k*IFSZ + col] : 0.0f;
    }
    if (tid < 256) sm[B_C1 + tid] = 0.0f;
  } else {
    for (int i = tid; i < NN*65;  i += 1024) sm[C_MS + i] = 0.0f;
    for (int i = tid; i < NN*129; i += 1024) sm[C_LS + i] = 0.0f;
    if (tid < 128){ sm[C_WW+tid]=0.f; sm[C_PRC+tid]=0.f; sm[C_USG+tid]=0.f; }
    if (tid < 512) sm[C_RWS+tid]=0.f;
  }
  __syncthreads();

  for (int t = 0; t <= TT; ++t){
    float* h0old = ws + W_H0 + (t&1)*8192;
    float* h0new = ws + W_H0 + ((t+1)&1)*8192;
    float* h1old = ws + W_H1 + (t&1)*8192;
    float* h1new = ws + W_H1 + ((t+1)&1)*8192;

    // ============ phase1: role A — outproj(t-1) + LSTM0 gates ============
    if (role == 0){
      float* Xs = sm + A_XS;
      if (t > 0){
        float accO[16];
        #pragma unroll
        for (int j=0;j<16;j++) accO[j]=0.f;
        for (int i = tid; i < 256*32; i += 1024){
          int k = i>>5, bb = i&31; Xs[k*36+bb] = gload(&gctl[i]);
        }
        __syncthreads();
        if (wid < 4){
          const int b0 = wid*8;
          #pragma unroll
          for (int i=0;i<4;i++){
            int k = lane*4 + i;
            float2 w2 = *reinterpret_cast<const float2*>(&sm[A_WO + k*2]);
            float4 x0 = *reinterpret_cast<const float4*>(&Xs[k*36+b0]);
            float4 x1 = *reinterpret_cast<const float4*>(&Xs[k*36+b0+4]);
            float xv[8] = {x0.x,x0.y,x0.z,x0.w,x1.x,x1.y,x1.z,x1.w};
            #pragma unroll
            for (int bi=0;bi<8;bi++){
              accO[bi*2]   += xv[bi]*w2.x;
              accO[bi*2+1] += xv[bi]*w2.y;
            }
          }
        }
        __syncthreads();
        for (int i = tid; i < 256*32; i += 1024){
          int k = i>>5, bb = i&31; Xs[k*36+bb] = gload(&greads[i]);
        }
        __syncthreads();
        if (wid < 4){
          const int b0 = wid*8;
          #pragma unroll
          for (int i=0;i<4;i++){
            int k = lane*4 + i;
            float2 w2 = *reinterpret_cast<const float2*>(&sm[A_WO + (256+k)*2]);
            float4 x0 = *reinterpret_cast<const float4*>(&Xs[k*36+b0]);
            float4 x1 = *reinterpret_cast<const float4*>(&Xs[k*36+b0+4]);
            float xv[8] = {x0.x,x0.y,x0.z,x0.w,x1.x,x1.y,x1.z,x1.w};
            #pragma unroll
            for (int bi=0;bi<8;bi++){
              accO[bi*2]   += xv[bi]*w2.x;
              accO[bi*2+1] += xv[bi]*w2.y;
            }
          }
          #pragma unroll
          for (int st=0; st<4; ++st){
            const int m = 1<<st, half = 8>>st;
            const bool hi = (lane & m) != 0;
            #pragma unroll
            for (int j=0;j<half;j++){
              float a = accO[j], b = accO[j+half];
              float keep = hi? b : a;
              float send = hi? a : b;
              accO[j] = keep + __shfl_xor(send, m, 64);
            }
          }
          accO[0] += __shfl_xor(accO[0], 16, 64);
          accO[0] += __shfl_xor(accO[0], 32, 64);
          int jb = ((lane&1)?8:0)|((lane&2)?4:0)|((lane&4)?2:0)|((lane&8)?1:0);
          if ((lane & 48) == 0){
            int bi = jb>>1, ci = jb&1;
            sm[A_GO + (wid*8+bi)*2 + ci] = accO[0];
          }
        }
        __syncthreads();
        if (tid < 64){
          int bb = tid>>1, c = tid&1;
          float v = sm[A_GO + tid] + boutg[2*g + c];
          outg[((t-1)*BB + bb)*OUTW + 2*g + c] = fminf(CLIPV, fmaxf(-CLIPV, v));
        }
        __syncthreads();
      }
      if (t < TT){
        float acc[64];
        #pragma unroll
        for (int j=0;j<64;j++) acc[j]=0.f;
        for (int i = tid; i < 64*32; i += 1024){
          int bb = i>>6, k = i&63;
          Xs[k*36+bb] = inputs[(t*BB + bb)*INW + k];
        }
        for (int i = tid; i < 256*32; i += 1024){
          int k = i>>5, bb = i&31;
          Xs[(64+k)*36+bb] = gload(&greads[i]);
        }
        __syncthreads();
        {
          const int b0 = (wid>>2)*8, c0 = (wid&3)*8;
          #pragma unroll
          for (int i=0;i<5;i++){
            int k = lane*5 + i;
            float4 w0 = *reinterpret_cast<const float4*>(&sm[A_WS + k*36+c0]);
            float4 w1 = *reinterpret_cast<const float4*>(&sm[A_WS + k*36+c0+4]);
            float4 x0 = *reinterpret_cast<const float4*>(&Xs[k*36+b0]);
            float4 x1 = *reinterpret_cast<const float4*>(&Xs[k*36+b0+4]);
            float xv[8] = {x0.x,x0.y,x0.z,x0.w,x1.x,x1.y,x1.z,x1.w};
            float wv[8] = {w0.x,w0.y,w0.z,w0.w,w1.x,w1.y,w1.z,w1.w};
            #pragma unroll
            for (int bi=0;bi<8;bi++)
              #pragma unroll
              for (int ci=0;ci<8;ci++)
                acc[bi*8+ci] += xv[bi]*wv[ci];
          }
        }
        __syncthreads();
        for (int i = tid; i < 256*32; i += 1024){
          int k = i>>5, bb = i&31; Xs[k*36+bb] = gload(&h0old[i]);
        }
        __syncthreads();
        {
          const int b0 = (wid>>2)*8, c0 = (wid&3)*8;
          #pragma unroll
          for (int i=0;i<4;i++){
            int k = lane*4 + i;
            float4 w0 = *reinterpret_cast<const float4*>(&sm[A_WS + (320+k)*36+c0]);
            float4 w1 = *reinterpret_cast<const float4*>(&sm[A_WS + (320+k)*36+c0+4]);
            float4 x0 = *reinterpret_cast<const float4*>(&Xs[k*36+b0]);
            float4 x1 = *reinterpret_cast<const float4*>(&Xs[k*36+b0+4]);
            float xv[8] = {x0.x,x0.y,x0.z,x0.w,x1.x,x1.y,x1.z,x1.w};
            float wv[8] = {w0.x,w0.y,w0.z,w0.w,w1.x,w1.y,w1.z,w1.w};
            #pragma unroll
            for (int bi=0;bi<8;bi++)
              #pragma unroll
              for (int ci=0;ci<8;ci++)
                acc[bi*8+ci] += xv[bi]*wv[ci];
          }
          int jb; float v = bfly64(acc, lane, &jb);
          const int b0w = (wid>>2)*8, c0w = (wid&3)*8;
          sm[A_GL + (b0w + (jb>>3))*32 + c0w + (jb&7)] = v;
        }
        __syncthreads();
        if (tid < 256){
          int bb = tid>>3, j = tid&7;
          float gi = sm[A_GL + bb*32 + j]      + b0g[8*g + j];
          float gf = sm[A_GL + bb*32 + 8 + j]  + b0g[256 + 8*g + j];
          float gg = sm[A_GL + bb*32 + 16 + j] + b0g[512 + 8*g + j];
          float go = sm[A_GL + bb*32 + 24 + j] + b0g[768 + 8*g + j];
          float c = sigf(gf)*sm[A_C0+tid] + sigf(gi)*tanhf(gg);
          sm[A_C0+tid] = c;
          gstore(&h0new[(8*g + j)*32 + bb], sigf(go)*tanhf(c));
        }
      }
    }
    if (t == TT) break;
    bar_t += NBLK; gbar(barw, bar_t);

    // ============ phase2: role B — LSTM1 gates ============
    if (role == 1){
      float* Xs = sm + B_XS;
      float acc[64];
      #pragma unroll
      for (int j=0;j<64;j++) acc[j]=0.f;
      for (int i = tid; i < 256*32; i += 1024){
        int k = i>>5, bb = i&31; Xs[k*36+bb] = gload(&h0new[i]);
      }
      __syncthreads();
      {
        const int b0 = (wid>>2)*8, c0 = (wid&3)*8;
        #pragma unroll
        for (int i=0;i<4;i++){
          int k = lane*4 + i;
          float4 w0 = *reinterpret_cast<const float4*>(&sm[B_W1 + k*36+c0]);
          float4 w1 = *reinterpret_cast<const float4*>(&sm[B_W1 + k*36+c0+4]);
          float4 x0 = *reinterpret_cast<const float4*>(&Xs[k*36+b0]);
          float4 x1 = *reinterpret_cast<const float4*>(&Xs[k*36+b0+4]);
          float xv[8] = {x0.x,x0.y,x0.z,x0.w,x1.x,x1.y,x1.z,x1.w};
          float wv[8] = {w0.x,w0.y,w0.z,w0.w,w1.x,w1.y,w1.z,w1.w};
          #pragma unroll
          for (int bi=0;bi<8;bi++)
            #pragma unroll
            for (int ci=0;ci<8;ci++)
              acc[bi*8+ci] += xv[bi]*wv[ci];
        }
      }
      __syncthreads();
      for (int i = tid; i < 256*32; i += 1024){
        int k = i>>5, bb = i&31; Xs[k*36+bb] = gload(&h1old[i]);
      }
      __syncthreads();
      {
        const int b0 = (wid>>2)*8, c0 = (wid&3)*8;
        #pragma unroll
        for (int i=0;i<4;i++){
          int k = lane*4 + i;
          float4 w0 = *reinterpret_cast<const float4*>(&sm[B_W1 + (256+k)*36+c0]);
          float4 w1 = *reinterpret_cast<const float4*>(&sm[B_W1 + (256+k)*36+c0+4]);
          float4 x0 = *reinterpret_cast<const float4*>(&Xs[k*36+b0]);
          float4 x1 = *reinterpret_cast<const float4*>(&Xs[k*36+b0+4]);
          float xv[8] = {x0.x,x0.y,x0.z,x0.w,x1.x,x1.y,x1.z,x1.w};
          float wv[8] = {w0.x,w0.y,w0.z,w0.w,w1.x,w1.y,w1.z,w1.w};
          #pragma unroll
          for (int bi=0;bi<8;bi++)
            #pragma unroll
            for (int ci=0;ci<8;ci++)
              acc[bi*8+ci] += xv[bi]*wv[ci];
        }
        int jb; float v = bfly64(acc, lane, &jb);
        const int b0w = (wid>>2)*8, c0w = (wid&3)*8;
        sm[B_GL + (b0w + (jb>>3))*32 + c0w + (jb&7)] = v;
      }
      __syncthreads();
      if (tid < 256){
        int bb = tid>>3, j = tid&7;
        float gi = sm[B_GL + bb*32 + j]      + b1g[8*g + j];
        float gf = sm[B_GL + bb*32 + 8 + j]  + b1g[256 + 8*g + j];
        float gg = sm[B_GL + bb*32 + 16 + j] + b1g[512 + 8*g + j];
        float go = sm[B_GL + bb*32 + 24 + j] + b1g[768 + 8*g + j];
        float c = sigf(gf)*sm[B_C1+tid] + sigf(gi)*tanhf(gg);
        sm[B_C1+tid] = c;
        float h = sigf(go)*tanhf(c);
        gstore(&h1new[(8*g + j)*32 + bb], h);
        gstore(&gctl[(8*g + j)*32 + bb], fminf(CLIPV, fmaxf(-CLIPV, h)));
      }
    }
    bar_t += NBLK; gbar(barw, bar_t);

    // ============ phase3: role B — interface vector ============
    if (role == 1){
      float* Xs = sm + B_XS;
      for (int i = tid; i < 256*32; i += 1024){
        int k = i>>5, bb = i&31; Xs[k*36+bb] = gload(&gctl[i]);
      }
      __syncthreads();
      if (wid < 8){
        float acc[64];
        #pragma unroll
        for (int j=0;j<64;j++) acc[j]=0.f;
        const int b0 = (wid>>1)*8, c0 = (wid&1)*8;
        #pragma unroll
        for (int i=0;i<4;i++){
          int k = lane*4 + i;
          float4 w0 = *reinterpret_cast<const float4*>(&sm[B_WIF + k*20+c0]);
          float4 w1 = *reinterpret_cast<const float4*>(&sm[B_WIF + k*20+c0+4]);
          float4 x0 = *reinterpret_cast<const float4*>(&Xs[k*36+b0]);
          float4 x1 = *reinterpret_cast<const float4*>(&Xs[k*36+b0+4]);
          float xv[8] = {x0.x,x0.y,x0.z,x0.w,x1.x,x1.y,x1.z,x1.w};
          float wv[8] = {w0.x,w0.y,w0.z,w0.w,w1.x,w1.y,w1.z,w1.w};
          #pragma unroll
          for (int bi=0;bi<8;bi++)
            #pragma unroll
            for (int ci=0;ci<8;ci++)
              acc[bi*8+ci] += xv[bi]*wv[ci];
        }
        int jb; float v = bfly64(acc, lane, &jb);
        int bi = jb>>3, ci = jb&7;
        int cl = c0 + ci;
        const int ncols = (g < 31) ? 15 : 6;
        if (cl < ncols){
          int col = g*15 + cl;
          gstore(&gifc[col*32 + (b0+bi)], v + bifg[col]);
        }
      }
    }
    bar_t += NBLK; gbar(barw, bar_t);

    // ============ phase4: role C — memory module (batch g) ============
    if (role == 2){
      float* Ms  = sm + C_MS;
      float* Ls  = sm + C_LS;
      float* wws = sm + C_WW;
      float* prc = sm + C_PRC;
      float* usg = sm + C_USG;
      float* rws = sm + C_RWS;
      float* ifcl= sm + C_IFC;
      float* fwds= sm + C_FWD;
      float* bwds= sm + C_BWD;
      float* u2  = sm + C_U2;
      float* wcs = sm + C_WCS;
      float* rcs = sm + C_RCS;
      float* mno = sm + C_MNO;
      float* rds = sm + C_RDS;
      float* ers = sm + C_ERS;
      float* wvs = sm + C_WVS;
      float* sc  = sm + C_SC;
      float* scal= sm + C_SCAL;

      if (tid < IFSZ) ifcl[tid] = gload(&gifc[tid*32 + g]);
      __syncthreads();
      if (tid < RR){
        scal[S_RSTR+tid]=1.0f+sofp(ifcl[OFF_RSTR+tid]);
        scal[S_FG+tid]  =sigf(ifcl[OFF_FG+tid]);
        float m0=ifcl[OFF_MD+tid*3], m1=ifcl[OFF_MD+tid*3+1], m2=ifcl[OFF_MD+tid*3+2];
        float mx=fmaxf(m0,fmaxf(m1,m2));
        float e0=expf(m0-mx), e1=expf(m1-mx), e2=expf(m2-mx);
        float s=e0+e1+e2;
        scal[S_BM+tid]=e0/s; scal[S_FM+tid]=e1/s; scal[S_CM+tid]=e2/s;
      }
      if (tid == 4) scal[S_WSTR]=1.0f+sofp(ifcl[OFF_WSTR]);
      if (tid == 5) scal[S_AG]=sigf(ifcl[OFF_AG]);
      if (tid == 6) scal[S_WG]=sigf(ifcl[OFF_WG]);
      if (tid >= 64 && tid < 128){
        int d=tid-64;
        ers[d]=sigf(ifcl[OFF_ER+d]);
        wvs[d]=ifcl[OFF_WV+d];
      }
      if (tid >= 128 && tid < 256){
        int n=tid-128; float s=0.f;
        #pragma unroll 8
        for (int d=0;d<WD;d++){ float v=Ms[n*65+d]; s+=v*v; }
        mno[n]=sqrtf(s);
      }
      if (wid == 8){
        float v=ifcl[OFF_WK+lane]; float s=wredSum(v*v);
        if (lane==0) scal[S_KNW]=sqrtf(s);
      }
      if (wid >= 10 && wid < 14){
        int r=wid-10; float v=ifcl[OFF_RK+r*WD+lane]; float s=wredSum(v*v);
        if (lane==0) scal[S_KNR+r]=sqrtf(s);
      }
      __syncthreads();
      if (tid < NN){
        float dot=0.f;
        #pragma unroll 8
        for (int d=0;d<WD;d++) dot += ifcl[OFF_WK+d]*Ms[tid*65+d];
        float sim = dot/(scal[S_KNW]*mno[tid]+EPSV);
        wcs[tid]=sim*scal[S_WSTR];
      }
      __syncthreads();
      if (tid < NN){ float mx=wredMax(wcs[tid]); if(lane==0) sc[wid]=mx; }
      __syncthreads();
      if (tid < NN){
        float mx=fmaxf(sc[0],sc[1]);
        float e=expf(wcs[tid]-mx);
        wcs[tid]=e;
        float s=wredSum(e); if(lane==0) sc[2+wid]=s;
      }
      __syncthreads();
      if (tid < NN) wcs[tid]=wcs[tid]/(sc[2]+sc[3]);
      __syncthreads();
      if (tid < NN){
        float cw = wws[tid];
        float u  = usg[tid] + (1.0f-usg[tid])*cw;
        float psi=1.0f;
        #pragma unroll
        for (int r=0;r<RR;r++) psi *= 1.0f - scal[S_FG+r]*rws[r*NN+tid];
        float us = u*psi;
        usg[tid]=us;
        u2[tid] = EPSV + (1.0f-EPSV)*us;
      }
      __syncthreads();
      if (tid < NN){
        float ui=u2[tid]; float p=1.0f;
        for (int j=0;j<NN;j++){
          float uj=u2[j];
          bool take = (uj<ui) || (uj==ui && j<tid);
          p *= take ? uj : 1.0f;
        }
        float a = (1.0f-ui)*p;
        float wwn = scal[S_WG]*( scal[S_AG]*a + (1.0f-scal[S_AG])*wcs[tid] );
        wws[tid]=wwn;
        float s=wredSum(wwn); if(lane==0) sc[wid]=s;
      }
      __syncthreads();
      if (tid==0) scal[S_WSUM]=sc[0]+sc[1];
      __syncthreads();
      #pragma unroll
      for (int i=0;i<8;i++){
        int el=tid+i*1024, n=el>>6, d=el&63;
        float w=wws[n];
        Ms[n*65+d] = Ms[n*65+d]*(1.0f - w*ers[d]) + w*wvs[d];
      }
      #pragma unroll
      for (int i=0;i<16;i++){
        int el=tid+i*1024, li=el>>7, lj=el&127;
        float v = (li==lj) ? 0.0f
                : (1.0f - wws[li] - wws[lj])*Ls[li*129+lj] + wws[li]*prc[lj];
        Ls[li*129+lj]=v;
      }
      __syncthreads();
      if (tid < NN) prc[tid] = (1.0f - scal[S_WSUM])*prc[tid] + wws[tid];
      if (tid >= 128 && tid < 256){
        int n=tid-128; float s=0.f;
        #pragma unroll 8
        for (int d=0;d<WD;d++){ float v=Ms[n*65+d]; s+=v*v; }
        mno[n]=sqrtf(s);
      }
      __syncthreads();
      if (tid < RR*NN){
        int r=tid>>7, n=tid&127;
        float dot=0.f;
        #pragma unroll 8
        for (int d=0;d<WD;d++) dot += ifcl[OFF_RK+r*WD+d]*Ms[n*65+d];
        float sim = dot/(scal[S_KNR+r]*mno[n]+EPSV);
        rcs[tid]=sim*scal[S_RSTR+r];
      }
      __syncthreads();
      if (tid < RR*NN){ float mx=wredMax(rcs[tid]); if(lane==0) sc[wid]=mx; }
      __syncthreads();
      if (tid < RR*NN){
        int r=tid>>7;
        float mx=fmaxf(sc[r*2],sc[r*2+1]);
        float e=expf(rcs[tid]-mx);
        rcs[tid]=e;
        float s=wredSum(e); if(lane==0) sc[8+wid]=s;
      }
      __syncthreads();
      if (tid < RR*NN){
        int r=tid>>7;
        rcs[tid]=rcs[tid]/(sc[8+r*2]+sc[9+r*2]);
      }
      __syncthreads();
      if (tid < RR*NN){
        int r=tid>>7, i=tid&127;
        float f=0.f, bw=0.f;
        const float* rwr = rws + r*NN;
        #pragma unroll 4
        for (int j=0;j<NN;j++){
          float rv=rwr[j];
          f  += Ls[i*129+j]*rv;
          bw += Ls[j*129+i]*rv;
        }
        fwds[tid]=f; bwds[tid]=bw;
      }
      __syncthreads();
      if (tid < RR*NN){
        int r=tid>>7;
        rws[tid] = scal[S_BM+r]*bwds[tid] + scal[S_CM+r]*rcs[tid] + scal[S_FM+r]*fwds[tid];
      }
      __syncthreads();
      if (tid < RR*WD){
        int r=tid>>6, d=tid&63;
        float s=0.f;
        #pragma unroll 8
        for (int n=0;n<NN;n++) s += rws[r*NN+n]*Ms[n*65+d];
        rds[tid]=s;
      }
      __syncthreads();
      if (tid < 256) gstore(&greads[tid*32 + g], rds[tid]);
    }
    bar_t += NBLK; gbar(barw, bar_t);
  }
}

extern "C" void kernel_launch(void* const* d_in, const int* in_sizes, int n_in,
                              void* d_out, int out_size, void* d_ws, size_t ws_size,
                              hipStream_t stream)
{
  const float* inputs=(const float*)d_in[0];
  const float* Wx0   =(const float*)d_in[1];
  const float* Wh0   =(const float*)d_in[2];
  const float* b0    =(const float*)d_in[3];
  const float* Wx1   =(const float*)d_in[4];
  const float* Wh1   =(const float*)d_in[5];
  const float* b1    =(const float*)d_in[6];
  const float* Wif   =(const float*)d_in[7];
  const float* bif   =(const float*)d_in[8];
  const float* Wout  =(const float*)d_in[9];
  const float* bout  =(const float*)d_in[10];
  float* out = (float*)d_out;
  float* ws  = (float*)d_ws;

  // zero state + barrier counter each call (graph-capture-safe, deterministic)
  hipMemsetAsync(ws, 0, (W_BAR + 64) * sizeof(float), stream);

  hipFuncSetAttribute((const void*)dnc_coop5,
                      hipFuncAttributeMaxDynamicSharedMemorySize, SMEM_BYTES);

  void* args[] = { (void*)&inputs, (void*)&Wx0, (void*)&Wh0, (void*)&b0,
                   (void*)&Wx1, (void*)&Wh1, (void*)&b1, (void*)&Wif,
                   (void*)&bif, (void*)&Wout, (void*)&bout, (void*)&out,
                   (void*)&ws };
  hipLaunchCooperativeKernel((void*)dnc_coop5, dim3(NBLK), dim3(1024),
                             args, SMEM_BYTES, stream);
}

// Round 7
// 4124.603 us; speedup vs baseline: 1.8861x; 1.5013x over previous
//
#include <hip/hip_runtime.h>
#include <math.h>

// DNC forward v7: R6 structure with the chunk2 X-row indexing bug fixed
// (TILE_FMA now takes separate W-row and X-row). 96 specialized blocks,
// weights LDS-resident, 3 two-level barriers/step, conflict-free GEMM
// (k = i*64+lane, LDS stride 37, scalar fragment loads), IF matvec in role C.

#define TT   64
#define BB   32
#define INW  64
#define OUTW 64
#define NN   128
#define WD   64
#define RR   4
#define HH   256
#define IFSZ 471
#define CLIPV 20.0f
#define EPSV  1e-6f
#define NBLK 96

// interface vector offsets
#define OFF_RK   0
#define OFF_RSTR 256
#define OFF_WK   260
#define OFF_WSTR 324
#define OFF_ER   325
#define OFF_WV   389
#define OFF_FG   453
#define OFF_AG   457
#define OFF_WG   458
#define OFF_MD   459

// scal slots
#define S_WSTR 0
#define S_AG   1
#define S_WG   2
#define S_KNW  3
#define S_WSUM 4
#define S_RSTR 8
#define S_FG   12
#define S_KNR  16
#define S_BM   20
#define S_FM   24
#define S_CM   28

// ---- LDS layouts (floats) ----
// role A: Xs[320][37], Gl[32][33], c0[256], GO[64], Ws[576][37], WO[512][3]
#define A_XS   0
#define A_GL   11840
#define A_C0   12896
#define A_GO   13152
#define A_WS   13216
#define A_WO   34528
// role B: Xs[256][37], Gl[32][33], c1[256], W1[512][37]
#define B_XS   0
#define B_GL   9472
#define B_C1   10528
#define B_W1   10784
// role C: memory module
#define C_MS   0
#define C_LS   8320
#define C_WW   24832
#define C_PRC  24960
#define C_USG  25088
#define C_RWS  25216
#define C_IFC  25728
#define C_FWD  26208    // also reused as part[1024] for the IF matvec
#define C_BWD  26720
#define C_U2   27232
#define C_WCS  27360
#define C_RCS  27488    // also reused as ctl_l[256] staging for IF
#define C_MNO  28000
#define C_RDS  28128
#define C_ERS  28384
#define C_WVS  28448
#define C_SC   28512
#define C_SCAL 28576

#define SMEM_FLOATS 36064
#define SMEM_BYTES  (SMEM_FLOATS*4)

// ---- ws layout (floats), state vectors transposed [k][b] ----
#define W_CTL  0       // [256][32]
#define W_RDS  8192    // [256][32]
#define W_H0   16384   // [2][256*32]
#define W_H1   32768   // [2][256*32]
#define W_BAR  49152   // barrier area: 8 group cnt (128B apart) + master + epoch
#define W_END  (W_BAR + 320)

__device__ __forceinline__ float sigf(float x){ return 1.0f/(1.0f+expf(-x)); }
__device__ __forceinline__ float sofp(float x){ return fmaxf(x,0.0f)+log1pf(expf(-fabsf(x))); }

__device__ __forceinline__ float gload(const float* p){
  return __hip_atomic_load(p, __ATOMIC_RELAXED, __HIP_MEMORY_SCOPE_AGENT);
}
__device__ __forceinline__ void gstore(float* p, float v){
  __hip_atomic_store(p, v, __ATOMIC_RELAXED, __HIP_MEMORY_SCOPE_AGENT);
}

// two-level grid barrier: 8 group counters (12 blocks each) -> master -> epoch.
__device__ __forceinline__ void gbar(unsigned* bar, int bid, unsigned target){
  asm volatile("s_waitcnt vmcnt(0)" ::: "memory");
  __syncthreads();
  if (threadIdx.x == 0){
    unsigned* gc = bar + (bid/12)*32;       // 128B-separated lines
    unsigned n = __hip_atomic_fetch_add(gc, 1u, __ATOMIC_RELAXED, __HIP_MEMORY_SCOPE_AGENT);
    if ((n % 12u) == 11u){
      unsigned m = __hip_atomic_fetch_add(bar + 256, 1u, __ATOMIC_RELAXED, __HIP_MEMORY_SCOPE_AGENT);
      if ((m % 8u) == 7u)
        __hip_atomic_store(bar + 288, (m/8u)+1u, __ATOMIC_RELAXED, __HIP_MEMORY_SCOPE_AGENT);
    }
    while (__hip_atomic_load(bar + 288, __ATOMIC_RELAXED, __HIP_MEMORY_SCOPE_AGENT) < target)
      __builtin_amdgcn_s_sleep(4);
  }
  __syncthreads();
}

__device__ __forceinline__ float wredSum(float v){
  #pragma unroll
  for (int m=32;m>0;m>>=1) v += __shfl_xor(v,m,64);
  return v;
}
__device__ __forceinline__ float wredMax(float v){
  #pragma unroll
  for (int m=32;m>0;m>>=1) v = fmaxf(v,__shfl_xor(v,m,64));
  return v;
}

// 6-stage butterfly reduce-scatter over 64 lanes
__device__ __forceinline__ float bfly64(float (&A)[64], int l, int* jb){
  #pragma unroll
  for (int st=0; st<6; ++st){
    const int m = 1<<st, half = 32>>st;
    const bool hi = (l & m) != 0;
    #pragma unroll
    for (int j=0;j<half;j++){
      float a = A[j], b = A[j+half];
      float keep = hi? b : a;
      float send = hi? a : b;
      A[j] = keep + __shfl_xor(send, m, 64);
    }
  }
  *jb = ((l&1)?32:0)|((l&2)?16:0)|((l&4)?8:0)|((l&8)?4:0)|((l&16)?2:0)|((l&32)?1:0);
  return A[0];
}

// 8x8 fragment FMA, scalar LDS loads (stride-37 rows -> conflict-free).
// WROW indexes the weight tile, XROW the staged activations (FIX vs R6).
#define TILE_FMA(WBASE, WROW, XROW)                                      \
  {                                                                      \
    float xv[8], wv[8];                                                  \
    _Pragma("unroll")                                                    \
    for (int q=0;q<8;q++){                                               \
      wv[q] = sm[(WBASE) + (WROW)*37 + c0 + q];                          \
      xv[q] = Xs[(XROW)*37 + b0 + q];                                    \
    }                                                                    \
    _Pragma("unroll")                                                    \
    for (int bi=0;bi<8;bi++)                                             \
      _Pragma("unroll")                                                  \
      for (int ci=0;ci<8;ci++)                                           \
        acc[bi*8+ci] += xv[bi]*wv[ci];                                   \
  }

extern "C" __global__ __launch_bounds__(1024, 1)
void dnc_coop7(const float* __restrict__ inputs,
               const float* __restrict__ Wx0, const float* __restrict__ Wh0, const float* __restrict__ b0g,
               const float* __restrict__ Wx1, const float* __restrict__ Wh1, const float* __restrict__ b1g,
               const float* __restrict__ Wifg, const float* __restrict__ bifg,
               const float* __restrict__ Woutg, const float* __restrict__ boutg,
               float* __restrict__ outg, float* __restrict__ ws)
{
  const int bid  = blockIdx.x;
  const int role = bid >> 5;   // 0,1,2
  const int g    = bid & 31;
  const int tid  = threadIdx.x;
  const int lane = tid & 63;
  const int wid  = tid >> 6;

  extern __shared__ float sm[];

  float* gctl  = ws + W_CTL;
  float* greads= ws + W_RDS;
  unsigned* barw = (unsigned*)(ws + W_BAR);
  unsigned bar_t = 0;

  // ---- one-time weight staging + state init (ws zeroed by host memset) ----
  if (role == 0){
    // Ws rows permuted: [Wx0 rows 64..319 | Wx0 rows 0..63 | Wh0 rows 0..255]
    // so that W row r multiplies Xs row r for Xs = [reads | x].
    for (int i = tid; i < 576*32; i += 1024){
      int r = i >> 5, cl = i & 31;
      int cglob = 8*g + (cl&7) + ((cl>>3)<<8);
      float v;
      if (r < 256)      v = Wx0[(64+r)*1024 + cglob];
      else if (r < 320) v = Wx0[(r-256)*1024 + cglob];
      else              v = Wh0[(r-320)*1024 + cglob];
      sm[A_WS + r*37 + cl] = v;
    }
    for (int i = tid; i < 512*2; i += 1024){
      int k = i >> 1, c = i & 1;
      sm[A_WO + k*3 + c] = Woutg[k*64 + 2*g + c];
    }
    if (tid < 256) sm[A_C0 + tid] = 0.0f;
  } else if (role == 1){
    for (int i = tid; i < 512*32; i += 1024){
      int r = i >> 5, cl = i & 31;
      int cglob = 8*g + (cl&7) + ((cl>>3)<<8);
      sm[B_W1 + r*37 + cl] = (r < 256) ? Wx1[r*1024 + cglob]
                                       : Wh1[(r-256)*1024 + cglob];
    }
    if (tid < 256) sm[B_C1 + tid] = 0.0f;
  } else {
    for (int i = tid; i < NN*65;  i += 1024) sm[C_MS + i] = 0.0f;
    for (int i = tid; i < NN*129; i += 1024) sm[C_LS + i] = 0.0f;
    if (tid < 128){ sm[C_WW+tid]=0.f; sm[C_PRC+tid]=0.f; sm[C_USG+tid]=0.f; }
    if (tid < 512) sm[C_RWS+tid]=0.f;
  }
  __syncthreads();

  for (int t = 0; t <= TT; ++t){
    float* h0old = ws + W_H0 + (t&1)*8192;
    float* h0new = ws + W_H0 + ((t+1)&1)*8192;
    float* h1old = ws + W_H1 + (t&1)*8192;
    float* h1new = ws + W_H1 + ((t+1)&1)*8192;

    // ============ phase1: role A — outproj(t-1) + LSTM0 gates ============
    if (role == 0){
      float* Xs = sm + A_XS;
      if (t > 0){
        float accO[16];
        #pragma unroll
        for (int j=0;j<16;j++) accO[j]=0.f;
        // stage ctl(t-1)
        for (int i = tid; i < 256*32; i += 1024){
          int k = i>>5, bb = i&31; Xs[k*37+bb] = gload(&gctl[i]);
        }
        __syncthreads();
        if (wid < 4){
          const int b0 = wid*8;
          #pragma unroll
          for (int i=0;i<4;i++){
            int k = i*64 + lane;
            float w0 = sm[A_WO + k*3], w1 = sm[A_WO + k*3 + 1];
            float xv[8];
            #pragma unroll
            for (int q=0;q<8;q++) xv[q] = Xs[k*37 + b0 + q];
            #pragma unroll
            for (int bi=0;bi<8;bi++){
              accO[bi*2]   += xv[bi]*w0;
              accO[bi*2+1] += xv[bi]*w1;
            }
          }
        }
        __syncthreads();
        // stage [reads(t-1) | x_t] (rows 0..255 reads, 256..319 x)
        for (int i = tid; i < 320*32; i += 1024){
          int k = i>>5, bb = i&31;
          float v;
          if (k < 256)      v = gload(&greads[i]);
          else if (t < TT)  v = inputs[(t*BB + bb)*INW + (k-256)];
          else              v = 0.0f;
          Xs[k*37+bb] = v;
        }
        __syncthreads();
        if (wid < 4){
          const int b0 = wid*8;
          #pragma unroll
          for (int i=0;i<4;i++){
            int k = i*64 + lane;
            float w0 = sm[A_WO + (256+k)*3], w1 = sm[A_WO + (256+k)*3 + 1];
            float xv[8];
            #pragma unroll
            for (int q=0;q<8;q++) xv[q] = Xs[k*37 + b0 + q];
            #pragma unroll
            for (int bi=0;bi<8;bi++){
              accO[bi*2]   += xv[bi]*w0;
              accO[bi*2+1] += xv[bi]*w1;
            }
          }
          // reduce: 4 scatter stages within 16-lane groups, 2 allreduce stages
          #pragma unroll
          for (int st=0; st<4; ++st){
            const int m = 1<<st, half = 8>>st;
            const bool hi = (lane & m) != 0;
            #pragma unroll
            for (int j=0;j<half;j++){
              float a = accO[j], b = accO[j+half];
              float keep = hi? b : a;
              float send = hi? a : b;
              accO[j] = keep + __shfl_xor(send, m, 64);
            }
          }
          accO[0] += __shfl_xor(accO[0], 16, 64);
          accO[0] += __shfl_xor(accO[0], 32, 64);
          int jb = ((lane&1)?8:0)|((lane&2)?4:0)|((lane&4)?2:0)|((lane&8)?1:0);
          if ((lane & 48) == 0){
            int bi = jb>>1, ci = jb&1;
            sm[A_GO + (wid*8+bi)*2 + ci] = accO[0];
          }
        }
        __syncthreads();
        if (tid < 64){
          int bb = tid>>1, c = tid&1;
          float v = sm[A_GO + tid] + boutg[2*g + c];
          outg[((t-1)*BB + bb)*OUTW + 2*g + c] = fminf(CLIPV, fmaxf(-CLIPV, v));
        }
      } else {
        // t==0: only stage [reads | x_0]
        for (int i = tid; i < 320*32; i += 1024){
          int k = i>>5, bb = i&31;
          Xs[k*37+bb] = (k < 256) ? gload(&greads[i])
                                  : inputs[(t*BB + bb)*INW + (k-256)];
        }
        __syncthreads();
      }
      if (t < TT){
        float acc[64];
        #pragma unroll
        for (int j=0;j<64;j++) acc[j]=0.f;
        {
          const int b0 = (wid>>2)*8, c0 = (wid&3)*8;
          #pragma unroll
          for (int i=0;i<5;i++){
            int k = i*64 + lane;
            TILE_FMA(A_WS, k, k)
          }
        }
        __syncthreads();
        // stage h0old (rows 0..255)
        for (int i = tid; i < 256*32; i += 1024){
          int k = i>>5, bb = i&31; Xs[k*37+bb] = gload(&h0old[i]);
        }
        __syncthreads();
        {
          const int b0 = (wid>>2)*8, c0 = (wid&3)*8;
          #pragma unroll
          for (int i=0;i<4;i++){
            int k = i*64 + lane;
            TILE_FMA(A_WS, 320+k, k)     // FIX: W row 320+k, X row k
          }
          int jb; float v = bfly64(acc, lane, &jb);
          sm[A_GL + (b0 + (jb>>3))*33 + c0 + (jb&7)] = v;
        }
        __syncthreads();
        if (tid < 256){
          int bb = tid>>3, j = tid&7;
          float gi = sm[A_GL + bb*33 + j]      + b0g[8*g + j];
          float gf = sm[A_GL + bb*33 + 8 + j]  + b0g[256 + 8*g + j];
          float gg = sm[A_GL + bb*33 + 16 + j] + b0g[512 + 8*g + j];
          float go = sm[A_GL + bb*33 + 24 + j] + b0g[768 + 8*g + j];
          float c = sigf(gf)*sm[A_C0+tid] + sigf(gi)*tanhf(gg);
          sm[A_C0+tid] = c;
          gstore(&h0new[(8*g + j)*32 + bb], sigf(go)*tanhf(c));
        }
      }
    }
    if (t == TT) break;
    bar_t += 1; gbar(barw, bid, bar_t);

    // ============ phase2: role B — LSTM1 gates ============
    if (role == 1){
      float* Xs = sm + B_XS;
      float acc[64];
      #pragma unroll
      for (int j=0;j<64;j++) acc[j]=0.f;
      for (int i = tid; i < 256*32; i += 1024){
        int k = i>>5, bb = i&31; Xs[k*37+bb] = gload(&h0new[i]);
      }
      __syncthreads();
      {
        const int b0 = (wid>>2)*8, c0 = (wid&3)*8;
        #pragma unroll
        for (int i=0;i<4;i++){
          int k = i*64 + lane;
          TILE_FMA(B_W1, k, k)
        }
      }
      __syncthreads();
      for (int i = tid; i < 256*32; i += 1024){
        int k = i>>5, bb = i&31; Xs[k*37+bb] = gload(&h1old[i]);
      }
      __syncthreads();
      {
        const int b0 = (wid>>2)*8, c0 = (wid&3)*8;
        #pragma unroll
        for (int i=0;i<4;i++){
          int k = i*64 + lane;
          TILE_FMA(B_W1, 256+k, k)       // FIX: W row 256+k, X row k
        }
        int jb; float v = bfly64(acc, lane, &jb);
        sm[B_GL + (b0 + (jb>>3))*33 + c0 + (jb&7)] = v;
      }
      __syncthreads();
      if (tid < 256){
        int bb = tid>>3, j = tid&7;
        float gi = sm[B_GL + bb*33 + j]      + b1g[8*g + j];
        float gf = sm[B_GL + bb*33 + 8 + j]  + b1g[256 + 8*g + j];
        float gg = sm[B_GL + bb*33 + 16 + j] + b1g[512 + 8*g + j];
        float go = sm[B_GL + bb*33 + 24 + j] + b1g[768 + 8*g + j];
        float c = sigf(gf)*sm[B_C1+tid] + sigf(gi)*tanhf(gg);
        sm[B_C1+tid] = c;
        float h = sigf(go)*tanhf(c);
        gstore(&h1new[(8*g + j)*32 + bb], h);
        gstore(&gctl[(8*g + j)*32 + bb], fminf(CLIPV, fmaxf(-CLIPV, h)));
      }
    }
    bar_t += 1; gbar(barw, bid, bar_t);

    // ============ phase3: role C — IF matvec + memory module (batch g) =====
    if (role == 2){
      float* Ms  = sm + C_MS;
      float* Ls  = sm + C_LS;
      float* wws = sm + C_WW;
      float* prc = sm + C_PRC;
      float* usg = sm + C_USG;
      float* rws = sm + C_RWS;
      float* ifcl= sm + C_IFC;
      float* fwds= sm + C_FWD;
      float* bwds= sm + C_BWD;
      float* u2  = sm + C_U2;
      float* wcs = sm + C_WCS;
      float* rcs = sm + C_RCS;
      float* mno = sm + C_MNO;
      float* rds = sm + C_RDS;
      float* ers = sm + C_ERS;
      float* wvs = sm + C_WVS;
      float* sc  = sm + C_SC;
      float* scal= sm + C_SCAL;
      float* ctl_l = sm + C_RCS;   // temp (rcs written later)
      float* part  = sm + C_FWD;   // temp [1024] (fwd/bwd written later)

      // IF: ifc = ctl @ Wif + bif, k split 2-way, Wif streamed from L2
      if (tid < 256) ctl_l[tid] = gload(&gctl[tid*32 + g]);
      __syncthreads();
      {
        const int kq = tid >> 9, c = tid & 511;
        if (c < IFSZ){
          const float* Wp = Wifg + (size_t)(kq*128)*IFSZ + c;
          const float* xp = ctl_l + kq*128;
          float a0=0.f, a1=0.f;
          #pragma unroll 8
          for (int k=0;k<128;k+=2){
            a0 += xp[k]   * Wp[(size_t)k*IFSZ];
            a1 += xp[k+1] * Wp[(size_t)(k+1)*IFSZ];
          }
          part[kq*512 + c] = a0 + a1;
        }
      }
      __syncthreads();
      if (tid < IFSZ) ifcl[tid] = part[tid] + part[512+tid] + bifg[tid];
      __syncthreads();

      if (tid < RR){
        scal[S_RSTR+tid]=1.0f+sofp(ifcl[OFF_RSTR+tid]);
        scal[S_FG+tid]  =sigf(ifcl[OFF_FG+tid]);
        float m0=ifcl[OFF_MD+tid*3], m1=ifcl[OFF_MD+tid*3+1], m2=ifcl[OFF_MD+tid*3+2];
        float mx=fmaxf(m0,fmaxf(m1,m2));
        float e0=expf(m0-mx), e1=expf(m1-mx), e2=expf(m2-mx);
        float s=e0+e1+e2;
        scal[S_BM+tid]=e0/s; scal[S_FM+tid]=e1/s; scal[S_CM+tid]=e2/s;
      }
      if (tid == 4) scal[S_WSTR]=1.0f+sofp(ifcl[OFF_WSTR]);
      if (tid == 5) scal[S_AG]=sigf(ifcl[OFF_AG]);
      if (tid == 6) scal[S_WG]=sigf(ifcl[OFF_WG]);
      if (tid >= 64 && tid < 128){
        int d=tid-64;
        ers[d]=sigf(ifcl[OFF_ER+d]);
        wvs[d]=ifcl[OFF_WV+d];
      }
      if (tid >= 128 && tid < 256){
        int n=tid-128; float s=0.f;
        #pragma unroll 8
        for (int d=0;d<WD;d++){ float v=Ms[n*65+d]; s+=v*v; }
        mno[n]=sqrtf(s);
      }
      if (wid == 8){
        float v=ifcl[OFF_WK+lane]; float s=wredSum(v*v);
        if (lane==0) scal[S_KNW]=sqrtf(s);
      }
      if (wid >= 10 && wid < 14){
        int r=wid-10; float v=ifcl[OFF_RK+r*WD+lane]; float s=wredSum(v*v);
        if (lane==0) scal[S_KNR+r]=sqrtf(s);
      }
      __syncthreads();
      if (tid < NN){
        float dot=0.f;
        #pragma unroll 8
        for (int d=0;d<WD;d++) dot += ifcl[OFF_WK+d]*Ms[tid*65+d];
        float sim = dot/(scal[S_KNW]*mno[tid]+EPSV);
        wcs[tid]=sim*scal[S_WSTR];
      }
      __syncthreads();
      if (tid < NN){ float mx=wredMax(wcs[tid]); if(lane==0) sc[wid]=mx; }
      __syncthreads();
      if (tid < NN){
        float mx=fmaxf(sc[0],sc[1]);
        float e=expf(wcs[tid]-mx);
        wcs[tid]=e;
        float s=wredSum(e); if(lane==0) sc[2+wid]=s;
      }
      __syncthreads();
      if (tid < NN) wcs[tid]=wcs[tid]/(sc[2]+sc[3]);
      __syncthreads();
      if (tid < NN){
        float cw = wws[tid];
        float u  = usg[tid] + (1.0f-usg[tid])*cw;
        float psi=1.0f;
        #pragma unroll
        for (int r=0;r<RR;r++) psi *= 1.0f - scal[S_FG+r]*rws[r*NN+tid];
        float us = u*psi;
        usg[tid]=us;
        u2[tid] = EPSV + (1.0f-EPSV)*us;
      }
      __syncthreads();
      if (tid < NN){
        float ui=u2[tid]; float p=1.0f;
        for (int j=0;j<NN;j++){
          float uj=u2[j];
          bool take = (uj<ui) || (uj==ui && j<tid);
          p *= take ? uj : 1.0f;
        }
        float a = (1.0f-ui)*p;
        float wwn = scal[S_WG]*( scal[S_AG]*a + (1.0f-scal[S_AG])*wcs[tid] );
        wws[tid]=wwn;
        float s=wredSum(wwn); if(lane==0) sc[wid]=s;
      }
      __syncthreads();
      if (tid==0) scal[S_WSUM]=sc[0]+sc[1];
      __syncthreads();
      #pragma unroll
      for (int i=0;i<8;i++){
        int el=tid+i*1024, n=el>>6, d=el&63;
        float w=wws[n];
        Ms[n*65+d] = Ms[n*65+d]*(1.0f - w*ers[d]) + w*wvs[d];
      }
      #pragma unroll
      for (int i=0;i<16;i++){
        int el=tid+i*1024, li=el>>7, lj=el&127;
        float v = (li==lj) ? 0.0f
                : (1.0f - wws[li] - wws[lj])*Ls[li*129+lj] + wws[li]*prc[lj];
        Ls[li*129+lj]=v;
      }
      __syncthreads();
      if (tid < NN) prc[tid] = (1.0f - scal[S_WSUM])*prc[tid] + wws[tid];
      if (tid >= 128 && tid < 256){
        int n=tid-128; float s=0.f;
        #pragma unroll 8
        for (int d=0;d<WD;d++){ float v=Ms[n*65+d]; s+=v*v; }
        mno[n]=sqrtf(s);
      }
      __syncthreads();
      if (tid < RR*NN){
        int r=tid>>7, n=tid&127;
        float dot=0.f;
        #pragma unroll 8
        for (int d=0;d<WD;d++) dot += ifcl[OFF_RK+r*WD+d]*Ms[n*65+d];
        float sim = dot/(scal[S_KNR+r]*mno[n]+EPSV);
        rcs[tid]=sim*scal[S_RSTR+r];
      }
      __syncthreads();
      if (tid < RR*NN){ float mx=wredMax(rcs[tid]); if(lane==0) sc[wid]=mx; }
      __syncthreads();
      if (tid < RR*NN){
        int r=tid>>7;
        float mx=fmaxf(sc[r*2],sc[r*2+1]);
        float e=expf(rcs[tid]-mx);
        rcs[tid]=e;
        float s=wredSum(e); if(lane==0) sc[8+wid]=s;
      }
      __syncthreads();
      if (tid < RR*NN){
        int r=tid>>7;
        rcs[tid]=rcs[tid]/(sc[8+r*2]+sc[9+r*2]);
      }
      __syncthreads();
      if (tid < RR*NN){
        int r=tid>>7, i=tid&127;
        float f=0.f, bw=0.f;
        const float* rwr = rws + r*NN;
        #pragma unroll 4
        for (int j=0;j<NN;j++){
          float rv=rwr[j];
          f  += Ls[i*129+j]*rv;
          bw += Ls[j*129+i]*rv;
        }
        fwds[tid]=f; bwds[tid]=bw;
      }
      __syncthreads();
      if (tid < RR*NN){
        int r=tid>>7;
        rws[tid] = scal[S_BM+r]*bwds[tid] + scal[S_CM+r]*rcs[tid] + scal[S_FM+r]*fwds[tid];
      }
      __syncthreads();
      if (tid < RR*WD){
        int r=tid>>6, d=tid&63;
        float s=0.f;
        #pragma unroll 8
        for (int n=0;n<NN;n++) s += rws[r*NN+n]*Ms[n*65+d];
        rds[tid]=s;
      }
      __syncthreads();
      if (tid < 256) gstore(&greads[tid*32 + g], rds[tid]);
    }
    bar_t += 1; gbar(barw, bid, bar_t);
  }
}

extern "C" void kernel_launch(void* const* d_in, const int* in_sizes, int n_in,
                              void* d_out, int out_size, void* d_ws, size_t ws_size,
                              hipStream_t stream)
{
  const float* inputs=(const float*)d_in[0];
  const float* Wx0   =(const float*)d_in[1];
  const float* Wh0   =(const float*)d_in[2];
  const float* b0    =(const float*)d_in[3];
  const float* Wx1   =(const float*)d_in[4];
  const float* Wh1   =(const float*)d_in[5];
  const float* b1    =(const float*)d_in[6];
  const float* Wif   =(const float*)d_in[7];
  const float* bif   =(const float*)d_in[8];
  const float* Wout  =(const float*)d_in[9];
  const float* bout  =(const float*)d_in[10];
  float* out = (float*)d_out;
  float* ws  = (float*)d_ws;

  // zero state + barrier counters each call (graph-capture-safe, deterministic)
  hipMemsetAsync(ws, 0, W_END * sizeof(float), stream);

  hipFuncSetAttribute((const void*)dnc_coop7,
                      hipFuncAttributeMaxDynamicSharedMemorySize, SMEM_BYTES);

  void* args[] = { (void*)&inputs, (void*)&Wx0, (void*)&Wh0, (void*)&b0,
                   (void*)&Wx1, (void*)&Wh1, (void*)&b1, (void*)&Wif,
                   (void*)&bif, (void*)&Wout, (void*)&bout, (void*)&out,
                   (void*)&ws };
  hipLaunchCooperativeKernel((void*)dnc_coop7, dim3(NBLK), dim3(1024),
                             args, SMEM_BYTES, stream);
}

// Round 8
// 3351.723 us; speedup vs baseline: 2.3210x; 1.2306x over previous
//
#include <hip/hip_runtime.h>
#include <math.h>

// DNC forward v8: R7 compute kernels, but the 3 grid barriers are replaced by
// point-to-point producer->consumer flags (per-block slots, wave-min poll),
// and independent GEMM chunks are precomputed in each role's idle window.
// Dep graph: A(t) <- {A,B,C}(t-1); B(t) <- A(t),B(t-1); C(t) <- B(t).

#define TT   64
#define BB   32
#define INW  64
#define OUTW 64
#define NN   128
#define WD   64
#define RR   4
#define HH   256
#define IFSZ 471
#define CLIPV 20.0f
#define EPSV  1e-6f
#define NBLK 96

// interface vector offsets
#define OFF_RK   0
#define OFF_RSTR 256
#define OFF_WK   260
#define OFF_WSTR 324
#define OFF_ER   325
#define OFF_WV   389
#define OFF_FG   453
#define OFF_AG   457
#define OFF_WG   458
#define OFF_MD   459

// scal slots
#define S_WSTR 0
#define S_AG   1
#define S_WG   2
#define S_KNW  3
#define S_WSUM 4
#define S_RSTR 8
#define S_FG   12
#define S_KNR  16
#define S_BM   20
#define S_FM   24
#define S_CM   28

// ---- LDS layouts (floats) ----
// role A: Xs[320][37], Gl[32][33], c0[256], GO[64], Ws[576][37], WO[512][3]
#define A_XS   0
#define A_GL   11840
#define A_C0   12896
#define A_GO   13152
#define A_WS   13216
#define A_WO   34528
// role B: Xs[256][37], Gl[32][33], c1[256], W1[512][37]
#define B_XS   0
#define B_GL   9472
#define B_C1   10528
#define B_W1   10784
// role C: memory module
#define C_MS   0
#define C_LS   8320
#define C_WW   24832
#define C_PRC  24960
#define C_USG  25088
#define C_RWS  25216
#define C_IFC  25728
#define C_FWD  26208    // also reused as part[1024] for the IF matvec
#define C_BWD  26720
#define C_U2   27232
#define C_WCS  27360
#define C_RCS  27488    // also reused as ctl_l[256] staging for IF
#define C_MNO  28000
#define C_RDS  28128
#define C_ERS  28384
#define C_WVS  28448
#define C_SC   28512
#define C_SCAL 28576

#define SMEM_FLOATS 36064
#define SMEM_BYTES  (SMEM_FLOATS*4)

// ---- ws layout (floats), state vectors transposed [k][b] ----
#define W_CTL  0       // [256][32]
#define W_RDS  8192    // [256][32]
#define W_H0   16384   // [2][256*32]
#define W_H1   32768   // [2][256*32]
#define W_FLA  49152   // fA: 32 slots x 32 floats (128B lines)
#define W_FLB  (W_FLA + 1024)
#define W_FLC  (W_FLB + 1024)
#define W_END  (W_FLC + 1024)

__device__ __forceinline__ float sigf(float x){ return 1.0f/(1.0f+expf(-x)); }
__device__ __forceinline__ float sofp(float x){ return fmaxf(x,0.0f)+log1pf(expf(-fabsf(x))); }

__device__ __forceinline__ float gload(const float* p){
  return __hip_atomic_load(p, __ATOMIC_RELAXED, __HIP_MEMORY_SCOPE_AGENT);
}
__device__ __forceinline__ void gstore(float* p, float v){
  __hip_atomic_store(p, v, __ATOMIC_RELAXED, __HIP_MEMORY_SCOPE_AGENT);
}

// wait until all 32 producer slots >= target. Wave 0 polls (32 parallel
// loads + wave-min), whole block releases at the trailing __syncthreads.
__device__ __forceinline__ void waitflag(const unsigned* slots, unsigned target){
  if (threadIdx.x < 64){
    for (;;){
      unsigned m = __hip_atomic_load(&slots[(threadIdx.x & 31)*32],
                                     __ATOMIC_RELAXED, __HIP_MEMORY_SCOPE_AGENT);
      #pragma unroll
      for (int s=32;s>0;s>>=1){
        unsigned o = (unsigned)__shfl_xor((int)m, s, 64);
        m = (o < m) ? o : m;
      }
      if (m >= target) break;
      __builtin_amdgcn_s_sleep(2);
    }
  }
  __syncthreads();
}

// publish: drain this block's stores, then post slot = val.
__device__ __forceinline__ void setflag(unsigned* slots, int g, unsigned val){
  asm volatile("s_waitcnt vmcnt(0)" ::: "memory");
  __syncthreads();   // all waves drained (compiler emits vmcnt(0) pre-barrier)
  if (threadIdx.x == 0)
    __hip_atomic_store(&slots[g*32], val, __ATOMIC_RELAXED, __HIP_MEMORY_SCOPE_AGENT);
}

__device__ __forceinline__ float wredSum(float v){
  #pragma unroll
  for (int m=32;m>0;m>>=1) v += __shfl_xor(v,m,64);
  return v;
}
__device__ __forceinline__ float wredMax(float v){
  #pragma unroll
  for (int m=32;m>0;m>>=1) v = fmaxf(v,__shfl_xor(v,m,64));
  return v;
}

// 6-stage butterfly reduce-scatter over 64 lanes
__device__ __forceinline__ float bfly64(float (&A)[64], int l, int* jb){
  #pragma unroll
  for (int st=0; st<6; ++st){
    const int m = 1<<st, half = 32>>st;
    const bool hi = (l & m) != 0;
    #pragma unroll
    for (int j=0;j<half;j++){
      float a = A[j], b = A[j+half];
      float keep = hi? b : a;
      float send = hi? a : b;
      A[j] = keep + __shfl_xor(send, m, 64);
    }
  }
  *jb = ((l&1)?32:0)|((l&2)?16:0)|((l&4)?8:0)|((l&8)?4:0)|((l&16)?2:0)|((l&32)?1:0);
  return A[0];
}

// 8x8 fragment FMA, scalar LDS loads (stride-37 rows -> conflict-free).
#define TILE_FMA(WBASE, WROW, XROW)                                      \
  {                                                                      \
    float xv[8], wv[8];                                                  \
    _Pragma("unroll")                                                    \
    for (int q=0;q<8;q++){                                               \
      wv[q] = sm[(WBASE) + (WROW)*37 + c0 + q];                          \
      xv[q] = Xs[(XROW)*37 + b0 + q];                                    \
    }                                                                    \
    _Pragma("unroll")                                                    \
    for (int bi=0;bi<8;bi++)                                             \
      _Pragma("unroll")                                                  \
      for (int ci=0;ci<8;ci++)                                           \
        acc[bi*8+ci] += xv[bi]*wv[ci];                                   \
  }

extern "C" __global__ __launch_bounds__(1024, 1)
void dnc_coop8(const float* __restrict__ inputs,
               const float* __restrict__ Wx0, const float* __restrict__ Wh0, const float* __restrict__ b0g,
               const float* __restrict__ Wx1, const float* __restrict__ Wh1, const float* __restrict__ b1g,
               const float* __restrict__ Wifg, const float* __restrict__ bifg,
               const float* __restrict__ Woutg, const float* __restrict__ boutg,
               float* __restrict__ outg, float* __restrict__ ws)
{
  const int bid  = blockIdx.x;
  const int role = bid >> 5;   // 0,1,2
  const int g    = bid & 31;
  const int tid  = threadIdx.x;
  const int lane = tid & 63;
  const int wid  = tid >> 6;

  extern __shared__ float sm[];

  float* gctl  = ws + W_CTL;
  float* greads= ws + W_RDS;
  unsigned* fA = (unsigned*)(ws + W_FLA);
  unsigned* fB = (unsigned*)(ws + W_FLB);
  unsigned* fC = (unsigned*)(ws + W_FLC);

  // ---- one-time weight staging + state init (ws zeroed by host memset) ----
  if (role == 0){
    // Ws rows: [0..255]=Wx0 rows 64..319 (reads), [256..319]=Wx0 rows 0..63 (x),
    // [320..575]=Wh0 rows 0..255 (h0).
    for (int i = tid; i < 576*32; i += 1024){
      int r = i >> 5, cl = i & 31;
      int cglob = 8*g + (cl&7) + ((cl>>3)<<8);
      float v;
      if (r < 256)      v = Wx0[(64+r)*1024 + cglob];
      else if (r < 320) v = Wx0[(r-256)*1024 + cglob];
      else              v = Wh0[(r-320)*1024 + cglob];
      sm[A_WS + r*37 + cl] = v;
    }
    for (int i = tid; i < 512*2; i += 1024){
      int k = i >> 1, c = i & 1;
      sm[A_WO + k*3 + c] = Woutg[k*64 + 2*g + c];
    }
    if (tid < 256) sm[A_C0 + tid] = 0.0f;
  } else if (role == 1){
    for (int i = tid; i < 512*32; i += 1024){
      int r = i >> 5, cl = i & 31;
      int cglob = 8*g + (cl&7) + ((cl>>3)<<8);
      sm[B_W1 + r*37 + cl] = (r < 256) ? Wx1[r*1024 + cglob]
                                       : Wh1[(r-256)*1024 + cglob];
    }
    if (tid < 256) sm[B_C1 + tid] = 0.0f;
  } else {
    for (int i = tid; i < NN*65;  i += 1024) sm[C_MS + i] = 0.0f;
    for (int i = tid; i < NN*129; i += 1024) sm[C_LS + i] = 0.0f;
    if (tid < 128){ sm[C_WW+tid]=0.f; sm[C_PRC+tid]=0.f; sm[C_USG+tid]=0.f; }
    if (tid < 512) sm[C_RWS+tid]=0.f;
  }
  __syncthreads();

  if (role == 0){
    // =================== ROLE A: outproj(t-1) + LSTM0 ===================
    float* Xs = sm + A_XS;
    for (int t = 0; t <= TT; ++t){
      float* h0old = ws + W_H0 + (t&1)*8192;
      float* h0new = ws + W_H0 + ((t+1)&1)*8192;
      float acc[64]; float accO[16];

      // --- idle-window work 1: h0-chunk + x-chunk (needs only fA(t)) ---
      waitflag(fA, (unsigned)t);          // all A stored h0old; trivially ok t=0
      if (t < TT){
        for (int i = tid; i < 256*32; i += 1024){
          int k = i>>5, bb = i&31; Xs[k*37+bb] = gload(&h0old[i]);
        }
        for (int i = tid; i < 64*32; i += 1024){
          int bb = i>>6, k = i&63;
          Xs[(256+k)*37+bb] = inputs[(t*BB + bb)*INW + k];
        }
        __syncthreads();
        #pragma unroll
        for (int j=0;j<64;j++) acc[j]=0.f;
        {
          const int b0 = (wid>>2)*8, c0 = (wid&3)*8;
          #pragma unroll
          for (int i=0;i<4;i++){
            int k = i*64 + lane;
            TILE_FMA(A_WS, 320+k, k)          // Wh0 @ h0old
          }
          TILE_FMA(A_WS, 256+lane, 256+lane)  // Wx(x) @ x_t
        }
        __syncthreads();                      // before restaging Xs
      }
      // --- idle-window work 2: outproj ctl-half (needs fB(t)) ---
      if (t > 0){
        waitflag(fB, (unsigned)t);
        for (int i = tid; i < 256*32; i += 1024){
          int k = i>>5, bb = i&31; Xs[k*37+bb] = gload(&gctl[i]);
        }
        __syncthreads();
        #pragma unroll
        for (int j=0;j<16;j++) accO[j]=0.f;
        if (wid < 4){
          const int b0 = wid*8;
          #pragma unroll
          for (int i=0;i<4;i++){
            int k = i*64 + lane;
            float w0 = sm[A_WO + k*3], w1 = sm[A_WO + k*3 + 1];
            float xv[8];
            #pragma unroll
            for (int q=0;q<8;q++) xv[q] = Xs[k*37 + b0 + q];
            #pragma unroll
            for (int bi=0;bi<8;bi++){
              accO[bi*2]   += xv[bi]*w0;
              accO[bi*2+1] += xv[bi]*w1;
            }
          }
        }
        __syncthreads();
      }
      // --- critical path: needs reads(t-1) from C ---
      waitflag(fC, (unsigned)t);
      for (int i = tid; i < 256*32; i += 1024){
        int k = i>>5, bb = i&31; Xs[k*37+bb] = gload(&greads[i]);
      }
      __syncthreads();
      if (t > 0){
        if (wid < 4){
          const int b0 = wid*8;
          #pragma unroll
          for (int i=0;i<4;i++){
            int k = i*64 + lane;
            float w0 = sm[A_WO + (256+k)*3], w1 = sm[A_WO + (256+k)*3 + 1];
            float xv[8];
            #pragma unroll
            for (int q=0;q<8;q++) xv[q] = Xs[k*37 + b0 + q];
            #pragma unroll
            for (int bi=0;bi<8;bi++){
              accO[bi*2]   += xv[bi]*w0;
              accO[bi*2+1] += xv[bi]*w1;
            }
          }
          #pragma unroll
          for (int st=0; st<4; ++st){
            const int m = 1<<st, half = 8>>st;
            const bool hi = (lane & m) != 0;
            #pragma unroll
            for (int j=0;j<half;j++){
              float a = accO[j], b = accO[j+half];
              float keep = hi? b : a;
              float send = hi? a : b;
              accO[j] = keep + __shfl_xor(send, m, 64);
            }
          }
          accO[0] += __shfl_xor(accO[0], 16, 64);
          accO[0] += __shfl_xor(accO[0], 32, 64);
          int jb = ((lane&1)?8:0)|((lane&2)?4:0)|((lane&4)?2:0)|((lane&8)?1:0);
          if ((lane & 48) == 0){
            int bi = jb>>1, ci = jb&1;
            sm[A_GO + (wid*8+bi)*2 + ci] = accO[0];
          }
        }
        __syncthreads();
        if (tid < 64){
          int bb = tid>>1, c = tid&1;
          float v = sm[A_GO + tid] + boutg[2*g + c];
          outg[((t-1)*BB + bb)*OUTW + 2*g + c] = fminf(CLIPV, fmaxf(-CLIPV, v));
        }
      }
      if (t == TT) break;
      {
        const int b0 = (wid>>2)*8, c0 = (wid&3)*8;
        #pragma unroll
        for (int i=0;i<4;i++){
          int k = i*64 + lane;
          TILE_FMA(A_WS, k, k)                // Wx(reads) @ reads
        }
        int jb; float v = bfly64(acc, lane, &jb);
        sm[A_GL + (b0 + (jb>>3))*33 + c0 + (jb&7)] = v;
      }
      __syncthreads();
      if (tid < 256){
        int bb = tid>>3, j = tid&7;
        float gi = sm[A_GL + bb*33 + j]      + b0g[8*g + j];
        float gf = sm[A_GL + bb*33 + 8 + j]  + b0g[256 + 8*g + j];
        float gg = sm[A_GL + bb*33 + 16 + j] + b0g[512 + 8*g + j];
        float go = sm[A_GL + bb*33 + 24 + j] + b0g[768 + 8*g + j];
        float c = sigf(gf)*sm[A_C0+tid] + sigf(gi)*tanhf(gg);
        sm[A_C0+tid] = c;
        gstore(&h0new[(8*g + j)*32 + bb], sigf(go)*tanhf(c));
      }
      setflag(fA, g, (unsigned)(t+1));
    }
  } else if (role == 1){
    // =================== ROLE B: LSTM1 ===================
    float* Xs = sm + B_XS;
    for (int t = 0; t < TT; ++t){
      float* h0new = ws + W_H0 + ((t+1)&1)*8192;
      float* h1old = ws + W_H1 + (t&1)*8192;
      float* h1new = ws + W_H1 + ((t+1)&1)*8192;
      float acc[64];
      #pragma unroll
      for (int j=0;j<64;j++) acc[j]=0.f;

      // --- idle-window: Wh1 @ h1old (needs only fB(t): other B done t-1) ---
      waitflag(fB, (unsigned)t);
      for (int i = tid; i < 256*32; i += 1024){
        int k = i>>5, bb = i&31; Xs[k*37+bb] = gload(&h1old[i]);
      }
      __syncthreads();
      {
        const int b0 = (wid>>2)*8, c0 = (wid&3)*8;
        #pragma unroll
        for (int i=0;i<4;i++){
          int k = i*64 + lane;
          TILE_FMA(B_W1, 256+k, k)
        }
      }
      __syncthreads();
      // --- critical path: needs h0new(t) from A ---
      waitflag(fA, (unsigned)(t+1));
      for (int i = tid; i < 256*32; i += 1024){
        int k = i>>5, bb = i&31; Xs[k*37+bb] = gload(&h0new[i]);
      }
      __syncthreads();
      {
        const int b0 = (wid>>2)*8, c0 = (wid&3)*8;
        #pragma unroll
        for (int i=0;i<4;i++){
          int k = i*64 + lane;
          TILE_FMA(B_W1, k, k)
        }
        int jb; float v = bfly64(acc, lane, &jb);
        sm[B_GL + (b0 + (jb>>3))*33 + c0 + (jb&7)] = v;
      }
      __syncthreads();
      if (tid < 256){
        int bb = tid>>3, j = tid&7;
        float gi = sm[B_GL + bb*33 + j]      + b1g[8*g + j];
        float gf = sm[B_GL + bb*33 + 8 + j]  + b1g[256 + 8*g + j];
        float gg = sm[B_GL + bb*33 + 16 + j] + b1g[512 + 8*g + j];
        float go = sm[B_GL + bb*33 + 24 + j] + b1g[768 + 8*g + j];
        float c = sigf(gf)*sm[B_C1+tid] + sigf(gi)*tanhf(gg);
        sm[B_C1+tid] = c;
        float h = sigf(go)*tanhf(c);
        gstore(&h1new[(8*g + j)*32 + bb], h);
        gstore(&gctl[(8*g + j)*32 + bb], fminf(CLIPV, fmaxf(-CLIPV, h)));
      }
      setflag(fB, g, (unsigned)(t+1));
    }
  } else {
    // =================== ROLE C: IF matvec + memory module (batch g) =====
    float* Ms  = sm + C_MS;
    float* Ls  = sm + C_LS;
    float* wws = sm + C_WW;
    float* prc = sm + C_PRC;
    float* usg = sm + C_USG;
    float* rws = sm + C_RWS;
    float* ifcl= sm + C_IFC;
    float* fwds= sm + C_FWD;
    float* bwds= sm + C_BWD;
    float* u2  = sm + C_U2;
    float* wcs = sm + C_WCS;
    float* rcs = sm + C_RCS;
    float* mno = sm + C_MNO;
    float* rds = sm + C_RDS;
    float* ers = sm + C_ERS;
    float* wvs = sm + C_WVS;
    float* sc  = sm + C_SC;
    float* scal= sm + C_SCAL;
    float* ctl_l = sm + C_RCS;   // temp (rcs written later)
    float* part  = sm + C_FWD;   // temp [1024] (fwd/bwd written later)

    for (int t = 0; t < TT; ++t){
      // --- idle-window: ||M(t-1)|| (local data, no wait) ---
      if (tid < 128){
        int n=tid; float s=0.f;
        #pragma unroll 8
        for (int d=0;d<WD;d++){ float v=Ms[n*65+d]; s+=v*v; }
        mno[n]=sqrtf(s);
      }
      // --- critical path: needs ctl(t) from B ---
      waitflag(fB, (unsigned)(t+1));
      if (tid < 256) ctl_l[tid] = gload(&gctl[tid*32 + g]);
      __syncthreads();
      {
        const int kq = tid >> 9, c = tid & 511;
        if (c < IFSZ){
          const float* Wp = Wifg + (size_t)(kq*128)*IFSZ + c;
          const float* xp = ctl_l + kq*128;
          float a0=0.f, a1=0.f;
          #pragma unroll 8
          for (int k=0;k<128;k+=2){
            a0 += xp[k]   * Wp[(size_t)k*IFSZ];
            a1 += xp[k+1] * Wp[(size_t)(k+1)*IFSZ];
          }
          part[kq*512 + c] = a0 + a1;
        }
      }
      __syncthreads();
      if (tid < IFSZ) ifcl[tid] = part[tid] + part[512+tid] + bifg[tid];
      __syncthreads();

      if (tid < RR){
        scal[S_RSTR+tid]=1.0f+sofp(ifcl[OFF_RSTR+tid]);
        scal[S_FG+tid]  =sigf(ifcl[OFF_FG+tid]);
        float m0=ifcl[OFF_MD+tid*3], m1=ifcl[OFF_MD+tid*3+1], m2=ifcl[OFF_MD+tid*3+2];
        float mx=fmaxf(m0,fmaxf(m1,m2));
        float e0=expf(m0-mx), e1=expf(m1-mx), e2=expf(m2-mx);
        float s=e0+e1+e2;
        scal[S_BM+tid]=e0/s; scal[S_FM+tid]=e1/s; scal[S_CM+tid]=e2/s;
      }
      if (tid == 4) scal[S_WSTR]=1.0f+sofp(ifcl[OFF_WSTR]);
      if (tid == 5) scal[S_AG]=sigf(ifcl[OFF_AG]);
      if (tid == 6) scal[S_WG]=sigf(ifcl[OFF_WG]);
      if (tid >= 64 && tid < 128){
        int d=tid-64;
        ers[d]=sigf(ifcl[OFF_ER+d]);
        wvs[d]=ifcl[OFF_WV+d];
      }
      if (wid == 8){
        float v=ifcl[OFF_WK+lane]; float s=wredSum(v*v);
        if (lane==0) scal[S_KNW]=sqrtf(s);
      }
      if (wid >= 10 && wid < 14){
        int r=wid-10; float v=ifcl[OFF_RK+r*WD+lane]; float s=wredSum(v*v);
        if (lane==0) scal[S_KNR+r]=sqrtf(s);
      }
      __syncthreads();
      if (tid < NN){
        float dot=0.f;
        #pragma unroll 8
        for (int d=0;d<WD;d++) dot += ifcl[OFF_WK+d]*Ms[tid*65+d];
        float sim = dot/(scal[S_KNW]*mno[tid]+EPSV);
        wcs[tid]=sim*scal[S_WSTR];
      }
      __syncthreads();
      if (tid < NN){ float mx=wredMax(wcs[tid]); if(lane==0) sc[wid]=mx; }
      __syncthreads();
      if (tid < NN){
        float mx=fmaxf(sc[0],sc[1]);
        float e=expf(wcs[tid]-mx);
        wcs[tid]=e;
        float s=wredSum(e); if(lane==0) sc[2+wid]=s;
      }
      __syncthreads();
      if (tid < NN) wcs[tid]=wcs[tid]/(sc[2]+sc[3]);
      __syncthreads();
      if (tid < NN){
        float cw = wws[tid];
        float u  = usg[tid] + (1.0f-usg[tid])*cw;
        float psi=1.0f;
        #pragma unroll
        for (int r=0;r<RR;r++) psi *= 1.0f - scal[S_FG+r]*rws[r*NN+tid];
        float us = u*psi;
        usg[tid]=us;
        u2[tid] = EPSV + (1.0f-EPSV)*us;
      }
      __syncthreads();
      if (tid < NN){
        float ui=u2[tid]; float p=1.0f;
        for (int j=0;j<NN;j++){
          float uj=u2[j];
          bool take = (uj<ui) || (uj==ui && j<tid);
          p *= take ? uj : 1.0f;
        }
        float a = (1.0f-ui)*p;
        float wwn = scal[S_WG]*( scal[S_AG]*a + (1.0f-scal[S_AG])*wcs[tid] );
        wws[tid]=wwn;
        float s=wredSum(wwn); if(lane==0) sc[wid]=s;
      }
      __syncthreads();
      if (tid==0) scal[S_WSUM]=sc[0]+sc[1];
      __syncthreads();
      #pragma unroll
      for (int i=0;i<8;i++){
        int el=tid+i*1024, n=el>>6, d=el&63;
        float w=wws[n];
        Ms[n*65+d] = Ms[n*65+d]*(1.0f - w*ers[d]) + w*wvs[d];
      }
      #pragma unroll
      for (int i=0;i<16;i++){
        int el=tid+i*1024, li=el>>7, lj=el&127;
        float v = (li==lj) ? 0.0f
                : (1.0f - wws[li] - wws[lj])*Ls[li*129+lj] + wws[li]*prc[lj];
        Ls[li*129+lj]=v;
      }
      __syncthreads();
      if (tid < NN) prc[tid] = (1.0f - scal[S_WSUM])*prc[tid] + wws[tid];
      if (tid >= 128 && tid < 256){
        int n=tid-128; float s=0.f;
        #pragma unroll 8
        for (int d=0;d<WD;d++){ float v=Ms[n*65+d]; s+=v*v; }
        mno[n]=sqrtf(s);
      }
      __syncthreads();
      if (tid < RR*NN){
        int r=tid>>7, n=tid&127;
        float dot=0.f;
        #pragma unroll 8
        for (int d=0;d<WD;d++) dot += ifcl[OFF_RK+r*WD+d]*Ms[n*65+d];
        float sim = dot/(scal[S_KNR+r]*mno[n]+EPSV);
        rcs[tid]=sim*scal[S_RSTR+r];
      }
      __syncthreads();
      if (tid < RR*NN){ float mx=wredMax(rcs[tid]); if(lane==0) sc[wid]=mx; }
      __syncthreads();
      if (tid < RR*NN){
        int r=tid>>7;
        float mx=fmaxf(sc[r*2],sc[r*2+1]);
        float e=expf(rcs[tid]-mx);
        rcs[tid]=e;
        float s=wredSum(e); if(lane==0) sc[8+wid]=s;
      }
      __syncthreads();
      if (tid < RR*NN){
        int r=tid>>7;
        rcs[tid]=rcs[tid]/(sc[8+r*2]+sc[9+r*2]);
      }
      __syncthreads();
      if (tid < RR*NN){
        int r=tid>>7, i=tid&127;
        float f=0.f, bw=0.f;
        const float* rwr = rws + r*NN;
        #pragma unroll 4
        for (int j=0;j<NN;j++){
          float rv=rwr[j];
          f  += Ls[i*129+j]*rv;
          bw += Ls[j*129+i]*rv;
        }
        fwds[tid]=f; bwds[tid]=bw;
      }
      __syncthreads();
      if (tid < RR*NN){
        int r=tid>>7;
        rws[tid] = scal[S_BM+r]*bwds[tid] + scal[S_CM+r]*rcs[tid] + scal[S_FM+r]*fwds[tid];
      }
      __syncthreads();
      if (tid < RR*WD){
        int r=tid>>6, d=tid&63;
        float s=0.f;
        #pragma unroll 8
        for (int n=0;n<NN;n++) s += rws[r*NN+n]*Ms[n*65+d];
        rds[tid]=s;
      }
      __syncthreads();
      if (tid < 256) gstore(&greads[tid*32 + g], rds[tid]);
      setflag(fC, g, (unsigned)(t+1));
    }
  }
}

extern "C" void kernel_launch(void* const* d_in, const int* in_sizes, int n_in,
                              void* d_out, int out_size, void* d_ws, size_t ws_size,
                              hipStream_t stream)
{
  const float* inputs=(const float*)d_in[0];
  const float* Wx0   =(const float*)d_in[1];
  const float* Wh0   =(const float*)d_in[2];
  const float* b0    =(const float*)d_in[3];
  const float* Wx1   =(const float*)d_in[4];
  const float* Wh1   =(const float*)d_in[5];
  const float* b1    =(const float*)d_in[6];
  const float* Wif   =(const float*)d_in[7];
  const float* bif   =(const float*)d_in[8];
  const float* Wout  =(const float*)d_in[9];
  const float* bout  =(const float*)d_in[10];
  float* out = (float*)d_out;
  float* ws  = (float*)d_ws;

  // zero state + flag slots each call (graph-capture-safe, deterministic)
  hipMemsetAsync(ws, 0, W_END * sizeof(float), stream);

  hipFuncSetAttribute((const void*)dnc_coop8,
                      hipFuncAttributeMaxDynamicSharedMemorySize, SMEM_BYTES);

  void* args[] = { (void*)&inputs, (void*)&Wx0, (void*)&Wh0, (void*)&b0,
                   (void*)&Wx1, (void*)&Wh1, (void*)&b1, (void*)&Wif,
                   (void*)&bif, (void*)&Wout, (void*)&bout, (void*)&out,
                   (void*)&ws };
  hipLaunchCooperativeKernel((void*)dnc_coop8, dim3(NBLK), dim3(1024),
                             args, SMEM_BYTES, stream);
}